// Round 2
// baseline (8333.841 us; speedup 1.0000x reference)
//
#include <hip/hip_runtime.h>

// Problem constants (fixed by the reference)
#define M_ROWS 106496   // 4096*26  (n,v) rows
#define NBATCH 4096
#define VN 26
#define KNUM 3
#define TS 25

typedef unsigned short u16;
typedef __attribute__((ext_vector_type(8))) short v8s;
typedef __attribute__((ext_vector_type(4))) float v4f;

__device__ __forceinline__ u16 f2bf(float f) {
    unsigned u = __float_as_uint(f);
    u += 0x7FFF + ((u >> 16) & 1);   // RNE
    return (u16)(u >> 16);
}
__device__ __forceinline__ float bf2f(u16 h) {
    return __uint_as_float(((unsigned)h) << 16);
}
__device__ __forceinline__ float sigm(float x) {
    return 1.f / (1.f + __expf(-x));
}
__device__ __forceinline__ float tanh_fast(float x) {
    return 2.f / (1.f + __expf(-2.f * x)) - 1.f;
}

// Async global->LDS, 16B per lane. LDS dest must be the wave-uniform base;
// HW adds lane*16. Staging layout stays LINEAR in lane order; the LDS
// swizzle is realized by pre-permuting the per-lane GLOBAL source chunk
// (rule: both-sides-or-neither with global_load_lds).
typedef const __attribute__((address_space(1))) unsigned int* gas_t;
typedef __attribute__((address_space(3))) unsigned int* las_t;
__device__ __forceinline__ void gl16(const void* g, void* l) {
    __builtin_amdgcn_global_load_lds((gas_t)g, (las_t)l, 16, 0, 0);
}

// ---------------------------------------------------------------------------
// Generic NT gemm: C[M,nc] = A[M,256](bf16) @ Bt[nc,256](bf16)^T + bias
// BM=128, BN=128, BK=32; 256 threads = 4 waves (2x2), each wave 64x64.
// 2-phase double-buffered pipeline (MEASURED faster for this kernel in R1).
// LDS chunk-XOR swizzle kills the ds_read_b128 bank conflicts.
// ACT=0: bias only. ACT=1: bias + leaky_relu(0.1).
// ---------------------------------------------------------------------------
template <int ACT>
__global__ __launch_bounds__(256) void gemm_nt(
    const u16* __restrict__ A, const u16* __restrict__ Bt,
    const float* __restrict__ bias, u16* __restrict__ C, int nc)
{
    __shared__ u16 Al[2][128 * 32];
    __shared__ u16 Bl[2][128 * 32];
    const int m0 = blockIdx.x * 128;
    const int n0 = blockIdx.y * 128;
    const int tid = threadIdx.x;
    const int wid = tid >> 6, lane = tid & 63;
    const int ln = lane & 15, q = lane >> 4;
    const int qs8 = (q ^ ((ln >> 1) & 3)) * 8;          // swizzled read chunk
    const int wm = (wid >> 1) * 64, wn = (wid & 1) * 64;
    const int srow = tid >> 2;
    const int spart = (tid & 3) ^ ((srow >> 1) & 3);    // swizzled src chunk

    const u16* gA0 = &A[(size_t)(m0 + srow) * 256 + spart * 8];
    const u16* gB0 = &Bt[(size_t)(n0 + srow) * 256 + spart * 8];

#define STG(b, kk) do {                                                     \
        gl16(gA0 + (kk) * 32,            &Al[b][wid * 512]);                \
        gl16(gA0 + 64 * 256 + (kk) * 32, &Al[b][2048 + wid * 512]);         \
        gl16(gB0 + (kk) * 32,            &Bl[b][wid * 512]);                \
        gl16(gB0 + 64 * 256 + (kk) * 32, &Bl[b][2048 + wid * 512]);         \
    } while (0)

    v4f acc[4][4] = {};
    STG(0, 0);
    __syncthreads();
#pragma unroll
    for (int kt = 0; kt < 8; ++kt) {
        const int cb = kt & 1, nb = cb ^ 1;
        if (kt < 7) STG(nb, kt + 1);
        v8s af[4], bfv[4];
#pragma unroll
        for (int i = 0; i < 4; ++i)
            af[i] = *(const v8s*)&Al[cb][(wm + i * 16 + ln) * 32 + qs8];
#pragma unroll
        for (int j = 0; j < 4; ++j)
            bfv[j] = *(const v8s*)&Bl[cb][(wn + j * 16 + ln) * 32 + qs8];
#pragma unroll
        for (int i = 0; i < 4; ++i)
#pragma unroll
            for (int j = 0; j < 4; ++j)
                acc[i][j] = __builtin_amdgcn_mfma_f32_16x16x32_bf16(
                    af[i], bfv[j], acc[i][j], 0, 0, 0);
        __syncthreads();
    }
#undef STG
#pragma unroll
    for (int i = 0; i < 4; ++i)
#pragma unroll
        for (int j = 0; j < 4; ++j) {
            int gc = n0 + wn + j * 16 + ln;
            float b = bias[gc];
#pragma unroll
            for (int r = 0; r < 4; ++r) {
                int gr = m0 + wm + i * 16 + q * 4 + r;
                float v = acc[i][j][r] + b;
                if (ACT) v = v > 0.f ? v : 0.1f * v;
                C[(size_t)gr * nc + gc] = f2bf(v);
            }
        }
}

// ---------------------------------------------------------------------------
// Graph mix: msg[(n,w),c] = sum_{k,v} y[(n,v),k*256+c] * aadj[k][v][w]
// ---------------------------------------------------------------------------
__global__ __launch_bounds__(256) void graph_mix(
    const u16* __restrict__ y, const float* __restrict__ aadj,
    u16* __restrict__ msg)
{
    __shared__ u16 yl[VN * 768];
    const int n = blockIdx.x, tid = threadIdx.x;
    const uint4* src = (const uint4*)(y + (size_t)n * VN * 768);
    for (int idx = tid; idx < VN * 768 / 8; idx += 256)
        ((uint4*)yl)[idx] = src[idx];
    __syncthreads();
    const int c = tid;
    float acc[VN] = {};
    for (int k = 0; k < KNUM; ++k)
        for (int v = 0; v < VN; ++v) {
            float yv = bf2f(yl[v * 768 + k * 256 + c]);
            const float* ap = &aadj[(k * VN + v) * VN];
#pragma unroll
            for (int w = 0; w < VN; ++w) acc[w] += yv * ap[w];
        }
    size_t base = (size_t)n * VN * 256;
    for (int w = 0; w < VN; ++w) msg[base + w * 256 + c] = f2bf(acc[w]);
}

// ---------------------------------------------------------------------------
// Fused GRU, K=288: cols 0..255 = msg (Wh*), 256..287 = xpad (x-proj + bias).
// REVERTED to the single-buffer two-barrier structure (R1's 2-phase dbuf
// measured 117->180 us slower at identical occupancy), keeping the R1 XOR
// swizzle (bank conflicts 4.9M -> 0) and strength-reduced staging addresses.
// grid = (832, 4); block = 128 rows x 64 cols x 3 gates.
// ---------------------------------------------------------------------------
__global__ __launch_bounds__(256) void gru_fused(
    const u16* __restrict__ Am, const u16* __restrict__ xpad,
    const u16* __restrict__ hprev, u16* __restrict__ hout,
    const u16* __restrict__ wfull, const u16* __restrict__ wxn)
{
    __shared__ u16 Al[128 * 32];   // 8 KB
    __shared__ u16 Bl[192 * 32];   // 12 KB
    __shared__ u16 Xl[64 * 32];    // 4 KB
    const int m0 = blockIdx.x * 128;
    const int n0 = blockIdx.y * 64;
    const int tid = threadIdx.x;
    const int wid = tid >> 6, lane = tid & 63;
    const int ln = lane & 15, q = lane >> 4;
    const int qs8 = (q ^ ((ln >> 1) & 3)) * 8;
    const int wm = (wid >> 1) * 64, wn = (wid & 1) * 32;
    const int srow = tid >> 2;
    const int spart = (tid & 3) ^ ((srow >> 1) & 3);

    const u16* gA0 = &Am[(size_t)(m0 + srow) * 256 + spart * 8];
    const u16* gB0 = &wfull[(size_t)(n0 + srow) * 288 + spart * 8];
    const u16* gX0 = &xpad[(size_t)(m0 + srow) * 32 + spart * 8];

    // wxn tile (64 rows of this block's n0 slice), consumed only at kt==8;
    // staged once, drained by the kt=0 barrier, never overwritten.
    gl16(&wxn[(size_t)(n0 + srow) * 32 + spart * 8], &Xl[wid * 512]);

    v4f accr[4][2] = {}, accz[4][2] = {}, acch[4][2] = {}, accn[4][2] = {};

#pragma unroll
    for (int kt = 0; kt < 9; ++kt) {
        if (kt < 8) {
            gl16(gA0 + kt * 32,            &Al[wid * 512]);
            gl16(gA0 + 64 * 256 + kt * 32, &Al[2048 + wid * 512]);
        } else {
            gl16(gX0,           &Al[wid * 512]);
            gl16(gX0 + 64 * 32, &Al[2048 + wid * 512]);
        }
        gl16(gB0 + kt * 32,             &Bl[wid * 512]);
        gl16(gB0 + 256 * 288 + kt * 32, &Bl[2048 + wid * 512]);
        gl16(gB0 + 512 * 288 + kt * 32, &Bl[4096 + wid * 512]);
        __syncthreads();

        v8s af[4];
#pragma unroll
        for (int i = 0; i < 4; ++i)
            af[i] = *(const v8s*)&Al[(wm + i * 16 + ln) * 32 + qs8];
        v8s bfr[3][2];
#pragma unroll
        for (int g = 0; g < 3; ++g)
#pragma unroll
            for (int j = 0; j < 2; ++j)
                bfr[g][j] = *(const v8s*)&Bl[(g * 64 + wn + j * 16 + ln) * 32 + qs8];
#pragma unroll
        for (int i = 0; i < 4; ++i)
#pragma unroll
            for (int j = 0; j < 2; ++j) {
                accr[i][j] = __builtin_amdgcn_mfma_f32_16x16x32_bf16(af[i], bfr[0][j], accr[i][j], 0, 0, 0);
                accz[i][j] = __builtin_amdgcn_mfma_f32_16x16x32_bf16(af[i], bfr[1][j], accz[i][j], 0, 0, 0);
                acch[i][j] = __builtin_amdgcn_mfma_f32_16x16x32_bf16(af[i], bfr[2][j], acch[i][j], 0, 0, 0);
            }
        if (kt == 8) {
            v8s bfn[2];
#pragma unroll
            for (int j = 0; j < 2; ++j)
                bfn[j] = *(const v8s*)&Xl[(wn + j * 16 + ln) * 32 + qs8];
#pragma unroll
            for (int i = 0; i < 4; ++i)
#pragma unroll
                for (int j = 0; j < 2; ++j)
                    accn[i][j] = __builtin_amdgcn_mfma_f32_16x16x32_bf16(af[i], bfn[j], accn[i][j], 0, 0, 0);
        }
        __syncthreads();
    }

#pragma unroll
    for (int i = 0; i < 4; ++i)
#pragma unroll
        for (int j = 0; j < 2; ++j) {
            int gc = n0 + wn + j * 16 + ln;
#pragma unroll
            for (int r = 0; r < 4; ++r) {
                int gr = m0 + wm + i * 16 + q * 4 + r;
                float rg = sigm(accr[i][j][r]);
                float zg = sigm(accz[i][j][r]);
                float nn = tanh_fast(accn[i][j][r] + rg * acch[i][j][r]);
                float hp = bf2f(hprev[(size_t)gr * 256 + gc]);
                hout[(size_t)gr * 256 + gc] = f2bf((1.f - zg) * nn + zg * hp);
            }
        }
}

// ---------------------------------------------------------------------------
// Head: res = hd2 @ W3^T + b3 ; pred = h1 + res ; write out[:, s], pnew,
// and next step's xpad row [pred, h2'-h3', pred-2h2'+h3', 1, 0...].
// ---------------------------------------------------------------------------
__global__ __launch_bounds__(256) void head_out(
    const u16* __restrict__ hd2, const float* __restrict__ w3,
    const float* __restrict__ b3, const float* __restrict__ p1,
    const float* __restrict__ p2, float* __restrict__ pnew,
    u16* __restrict__ xpad, float* __restrict__ out, int s)
{
    __shared__ u16 hl[32 * 256];
    __shared__ float w3l[3 * 256];
    const int bm = blockIdx.x, tid = threadIdx.x;
    const uint4* src = (const uint4*)(hd2 + (size_t)bm * 32 * 256);
    for (int idx = tid; idx < 1024; idx += 256) ((uint4*)hl)[idx] = src[idx];
    for (int idx = tid; idx < 768; idx += 256) w3l[idx] = w3[idx];
    __syncthreads();
    const int r = tid >> 3, l8 = tid & 7;
    float s0 = 0.f, s1 = 0.f, s2 = 0.f;
    for (int c = l8 * 32; c < l8 * 32 + 32; ++c) {
        float hv = bf2f(hl[r * 256 + c]);
        s0 += hv * w3l[c];
        s1 += hv * w3l[256 + c];
        s2 += hv * w3l[512 + c];
    }
    for (int off = 1; off < 8; off <<= 1) {
        s0 += __shfl_xor(s0, off, 8);
        s1 += __shfl_xor(s1, off, 8);
        s2 += __shfl_xor(s2, off, 8);
    }
    // butterfly leaves the full sums in ALL 8 lanes
    const int m = bm * 32 + r;
    float a0 = p1[m * 3 + 0], a1 = p1[m * 3 + 1], a2 = p1[m * 3 + 2];
    float c0 = p2[m * 3 + 0], c1 = p2[m * 3 + 1], c2 = p2[m * 3 + 2];
    float o0 = a0 + s0 + b3[0];
    float o1 = a1 + s1 + b3[1];
    float o2 = a2 + s2 + b3[2];
    if (l8 == 0) {
        size_t ob = ((size_t)m * TS + s) * 3;
        out[ob + 0] = o0; out[ob + 1] = o1; out[ob + 2] = o2;
        pnew[m * 3 + 0] = o0; pnew[m * 3 + 1] = o1; pnew[m * 3 + 2] = o2;
    }
    // next x: ins_p=pred, ins_v=p1-p2, ins_a=pred-2*p1+p2, col9=1, rest 0
    u16 xv[4];
#pragma unroll
    for (int t = 0; t < 4; ++t) {
        int c = l8 * 4 + t;
        float v = 0.f;
        if (c == 0) v = o0; else if (c == 1) v = o1; else if (c == 2) v = o2;
        else if (c == 3) v = a0 - c0; else if (c == 4) v = a1 - c1;
        else if (c == 5) v = a2 - c2;
        else if (c == 6) v = o0 - 2.f * a0 + c0;
        else if (c == 7) v = o1 - 2.f * a1 + c1;
        else if (c == 8) v = o2 - 2.f * a2 + c2;
        else if (c == 9) v = 1.f;
        xv[t] = f2bf(v);
    }
    uint2 pk;
    pk.x = (unsigned)xv[0] | ((unsigned)xv[1] << 16);
    pk.y = (unsigned)xv[2] | ((unsigned)xv[3] << 16);
    ((uint2*)&xpad[(size_t)m * 32])[l8] = pk;
}

// ---------------------------------------------------------------------------
// Step-0 xpad from the three input frames.
// ---------------------------------------------------------------------------
__global__ __launch_bounds__(256) void init_xpad(
    const float* __restrict__ x0, const float* __restrict__ xp,
    const float* __restrict__ xp2, u16* __restrict__ xpad)
{
    int m = blockIdx.x * 256 + threadIdx.x;
    float a0 = x0[m * 3 + 0], a1 = x0[m * 3 + 1], a2 = x0[m * 3 + 2];
    float b0 = xp[m * 3 + 0], b1 = xp[m * 3 + 1], b2 = xp[m * 3 + 2];
    float c0 = xp2[m * 3 + 0], c1 = xp2[m * 3 + 1], c2 = xp2[m * 3 + 2];
    unsigned t[32];
#pragma unroll
    for (int i = 0; i < 32; ++i) t[i] = 0;
    t[0] = f2bf(a0); t[1] = f2bf(a1); t[2] = f2bf(a2);
    t[3] = f2bf(b0 - c0); t[4] = f2bf(b1 - c1); t[5] = f2bf(b2 - c2);
    t[6] = f2bf(a0 - 2.f * b0 + c0);
    t[7] = f2bf(a1 - 2.f * b1 + c1);
    t[8] = f2bf(a2 - 2.f * b2 + c2);
    t[9] = f2bf(1.f);
    uint4* dst = (uint4*)&xpad[(size_t)m * 32];
#pragma unroll
    for (int wq = 0; wq < 4; ++wq) {
        uint4 u;
        u.x = t[wq * 8 + 0] | (t[wq * 8 + 1] << 16);
        u.y = t[wq * 8 + 2] | (t[wq * 8 + 3] << 16);
        u.z = t[wq * 8 + 4] | (t[wq * 8 + 5] << 16);
        u.w = t[wq * 8 + 6] | (t[wq * 8 + 7] << 16);
        dst[wq] = u;
    }
}

// ---------------------------------------------------------------------------
// hidden [N,C,V] fp32 -> h[(n,v),c] bf16.
// ---------------------------------------------------------------------------
__global__ __launch_bounds__(256) void transpose_h(
    const float* __restrict__ hidden, u16* __restrict__ hA)
{
    __shared__ float hl[256 * VN];
    const int n = blockIdx.x, tid = threadIdx.x;
    const uint4* src = (const uint4*)(hidden + (size_t)n * 256 * VN);
    for (int idx = tid; idx < 256 * VN / 4; idx += 256)
        ((uint4*)hl)[idx] = src[idx];
    __syncthreads();
    size_t base = (size_t)n * VN * 256;
    for (int idx = tid; idx < VN * 256; idx += 256) {
        int v = idx >> 8, c = idx & 255;
        hA[base + idx] = f2bf(hl[c * VN + v]);
    }
}

// ---------------------------------------------------------------------------
// Weight packing (once per call).
// wfull[768,288]: row g*256+c -> cols 0..255 = Wh_g[c,:],
//   256..264 = x-weights (g<2), 265 = bias (g<2), rest 0.
// wxn[256,32]:   row c -> 0..8 = Win[c,:], 9 = b_in[c], rest 0.
// ---------------------------------------------------------------------------
__global__ __launch_bounds__(256) void pack_weights(
    const float* __restrict__ Whr, const float* __restrict__ Whi,
    const float* __restrict__ Whh, const float* __restrict__ convw_f,
    const float* __restrict__ W1f, const float* __restrict__ W2f,
    const float* __restrict__ Af, const float* __restrict__ emul,
    const float* __restrict__ eadd, const float* __restrict__ Wir,
    const float* __restrict__ Wii, const float* __restrict__ Win,
    const float* __restrict__ bir, const float* __restrict__ bii,
    const float* __restrict__ b_in, const float* __restrict__ convb_f,
    const float* __restrict__ b1f, const float* __restrict__ b2f,
    const float* __restrict__ W3f, const float* __restrict__ b3f,
    u16* __restrict__ wfull, u16* __restrict__ wxn, u16* __restrict__ convw,
    u16* __restrict__ w1, u16* __restrict__ w2, float* __restrict__ aadj,
    float* __restrict__ convb, float* __restrict__ b1, float* __restrict__ b2,
    float* __restrict__ w3, float* __restrict__ b3)
{
    int gid = blockIdx.x * 256 + threadIdx.x;
    int stride = gridDim.x * 256;
    for (int i = gid; i < 768 * 288; i += stride) {
        int row = i / 288, col = i - row * 288;
        int g = row >> 8, c = row & 255;
        float v = 0.f;
        if (col < 256)
            v = (g == 0 ? Whr : (g == 1 ? Whi : Whh))[c * 256 + col];
        else if (col < 265) {
            int tcol = col - 256;
            v = (g == 0 ? Wir[c * 9 + tcol] : (g == 1 ? Wii[c * 9 + tcol] : 0.f));
        } else if (col == 265)
            v = (g == 0 ? bir[c] : (g == 1 ? bii[c] : 0.f));
        wfull[i] = f2bf(v);
    }
    for (int i = gid; i < 256 * 32; i += stride) {
        int c = i >> 5, col = i & 31;
        float v = 0.f;
        if (col < 9) v = Win[c * 9 + col];
        else if (col == 9) v = b_in[c];
        wxn[i] = f2bf(v);
    }
    for (int i = gid; i < 65536; i += stride) {
        w1[i] = f2bf(W1f[i]);
        w2[i] = f2bf(W2f[i]);
    }
    for (int i = gid; i < 196608; i += stride) convw[i] = f2bf(convw_f[i]);
    for (int i = gid; i < KNUM * VN * VN; i += stride)
        aadj[i] = Af[i] * emul[i] + eadd[i];
    for (int i = gid; i < 256; i += stride) { b1[i] = b1f[i]; b2[i] = b2f[i]; }
    for (int i = gid; i < 768; i += stride) { convb[i] = convb_f[i]; w3[i] = W3f[i]; }
    if (gid < 3) b3[gid] = b3f[gid];
}

// ---------------------------------------------------------------------------
extern "C" void kernel_launch(void* const* d_in, const int* in_sizes, int n_in,
                              void* d_out, int out_size, void* d_ws, size_t ws_size,
                              hipStream_t stream)
{
    const float* inputs   = (const float*)d_in[0];
    const float* inputs_p = (const float*)d_in[1];
    const float* inputs_p2= (const float*)d_in[2];
    const float* hidden   = (const float*)d_in[3];
    const float* Af       = (const float*)d_in[4];
    const float* emul     = (const float*)d_in[5];
    const float* eadd     = (const float*)d_in[6];
    const float* conv_w   = (const float*)d_in[7];
    const float* conv_b   = (const float*)d_in[8];
    const float* Wir      = (const float*)d_in[9];
    const float* bir      = (const float*)d_in[10];
    const float* Wii      = (const float*)d_in[11];
    const float* bii      = (const float*)d_in[12];
    const float* Win      = (const float*)d_in[13];
    const float* b_in     = (const float*)d_in[14];
    const float* Whr      = (const float*)d_in[15];
    const float* Whi      = (const float*)d_in[16];
    const float* Whh      = (const float*)d_in[17];
    const float* W1f      = (const float*)d_in[18];
    const float* b1f      = (const float*)d_in[19];
    const float* W2f      = (const float*)d_in[20];
    const float* b2f      = (const float*)d_in[21];
    const float* W3f      = (const float*)d_in[22];
    const float* b3f      = (const float*)d_in[23];
    float* out = (float*)d_out;

    const size_t M = M_ROWS;
    char* ws = (char*)d_ws;
    size_t off = 0;
    auto alloc = [&](size_t bytes) -> void* {
        void* p = ws + off;
        off = (off + bytes + 255) & ~(size_t)255;
        return p;
    };
    u16* hA    = (u16*)alloc(M * 256 * 2);
    u16* hB    = (u16*)alloc(M * 256 * 2);
    u16* msg   = (u16*)alloc(M * 256 * 2);
    u16* ybuf  = (u16*)alloc(M * 768 * 2);
    u16* xpad  = (u16*)alloc(M * 32 * 2);
    float* pa  = (float*)alloc(M * 3 * 4);
    float* pb  = (float*)alloc(M * 3 * 4);
    float* pc  = (float*)alloc(M * 3 * 4);
    u16* wfull = (u16*)alloc(768 * 288 * 2);
    u16* wxn   = (u16*)alloc(256 * 32 * 2);
    u16* convw = (u16*)alloc(196608 * 2);
    u16* w1    = (u16*)alloc(65536 * 2);
    u16* w2    = (u16*)alloc(65536 * 2);
    float* aadj  = (float*)alloc(KNUM * VN * VN * 4);
    float* convb = (float*)alloc(768 * 4);
    float* b1    = (float*)alloc(256 * 4);
    float* b2    = (float*)alloc(256 * 4);
    float* w3    = (float*)alloc(768 * 4);
    float* b3    = (float*)alloc(16);
    if (off > ws_size) return;

    pack_weights<<<512, 256, 0, stream>>>(
        Whr, Whi, Whh, conv_w, W1f, W2f, Af, emul, eadd, Wir, Wii, Win,
        bir, bii, b_in, conv_b, b1f, b2f, W3f, b3f,
        wfull, wxn, convw, w1, w2, aadj, convb, b1, b2, w3, b3);
    transpose_h<<<NBATCH, 256, 0, stream>>>(hidden, hA);
    init_xpad<<<M_ROWS / 256, 256, 0, stream>>>(inputs, inputs_p, inputs_p2, xpad);
    hipMemcpyAsync(pa, inputs,    M * 3 * 4, hipMemcpyDeviceToDevice, stream);
    hipMemcpyAsync(pb, inputs_p,  M * 3 * 4, hipMemcpyDeviceToDevice, stream);
    hipMemcpyAsync(pc, inputs_p2, M * 3 * 4, hipMemcpyDeviceToDevice, stream);

    u16* hcur = hA;  u16* hnext = hB;
    float* P1 = pa;  float* P2 = pb;  float* P3 = pc;
    u16* hd  = ybuf;
    u16* hd2 = ybuf + M * 256;
    const int MB = M_ROWS / 128;  // 832

    for (int s = 0; s < TS; ++s) {
        const u16* m_ptr;
        if (s < 10) {
            gemm_nt<0><<<dim3(MB, 6), 256, 0, stream>>>(hcur, convw, convb, ybuf, 768);
            graph_mix<<<NBATCH, 256, 0, stream>>>(ybuf, aadj, msg);
            m_ptr = msg;
        } else {
            m_ptr = hcur;
        }
        gru_fused<<<dim3(MB, 4), 256, 0, stream>>>(m_ptr, xpad, hcur, hnext,
                                                   wfull, wxn);
        gemm_nt<1><<<dim3(MB, 2), 256, 0, stream>>>(hnext, w1, b1, hd, 256);
        gemm_nt<1><<<dim3(MB, 2), 256, 0, stream>>>(hd, w2, b2, hd2, 256);
        // head also emits xpad for step s+1
        head_out<<<M_ROWS / 32, 256, 0, stream>>>(hd2, w3, b3, P1, P2, P3,
                                                  xpad, out, s);
        float* t = P3; P3 = P2; P2 = P1; P1 = t;
        u16* ht = hcur; hcur = hnext; hnext = ht;
    }
}

// Round 3
// 6946.328 us; speedup vs baseline: 1.1997x; 1.1997x over previous
//
#include <hip/hip_runtime.h>

// Problem constants (fixed by the reference)
#define M_ROWS 106496   // 4096*26  (n,v) rows
#define NBATCH 4096
#define VN 26
#define KNUM 3
#define TS 25

typedef unsigned short u16;
typedef __attribute__((ext_vector_type(8))) short v8s;
typedef __attribute__((ext_vector_type(4))) float v4f;

__device__ __forceinline__ u16 f2bf(float f) {
    unsigned u = __float_as_uint(f);
    u += 0x7FFF + ((u >> 16) & 1);   // RNE
    return (u16)(u >> 16);
}
__device__ __forceinline__ float bf2f(u16 h) {
    return __uint_as_float(((unsigned)h) << 16);
}
__device__ __forceinline__ float sigm(float x) {
    return 1.f / (1.f + __expf(-x));
}
__device__ __forceinline__ float tanh_fast(float x) {
    return 2.f / (1.f + __expf(-2.f * x)) - 1.f;
}

// Async global->LDS, 16B per lane. LDS dest must be the wave-uniform base;
// HW adds lane*16. Staging layout stays LINEAR in lane order; the LDS
// swizzle is realized by pre-permuting the per-lane GLOBAL source chunk
// (rule: both-sides-or-neither with global_load_lds).
typedef const __attribute__((address_space(1))) unsigned int* gas_t;
typedef __attribute__((address_space(3))) unsigned int* las_t;
__device__ __forceinline__ void gl16(const void* g, void* l) {
    __builtin_amdgcn_global_load_lds((gas_t)g, (las_t)l, 16, 0, 0);
}

// ---------------------------------------------------------------------------
// Generic NT gemm: C[M,nc] = A[M,256](bf16) @ Bt[nc,256](bf16)^T + bias
// BM=128, BN=128, BK=32; 256 threads = 4 waves (2x2), each wave 64x64.
// 2-phase double-buffered pipeline (MEASURED faster for this kernel in R1:
// non-gru time 4131 -> ~3200-3400 us). LDS chunk-XOR swizzle kills the
// ds_read_b128 bank conflicts. DO NOT TOUCH without an A/B.
// ACT=0: bias only. ACT=1: bias + leaky_relu(0.1).
// ---------------------------------------------------------------------------
template <int ACT>
__global__ __launch_bounds__(256) void gemm_nt(
    const u16* __restrict__ A, const u16* __restrict__ Bt,
    const float* __restrict__ bias, u16* __restrict__ C, int nc)
{
    __shared__ u16 Al[2][128 * 32];
    __shared__ u16 Bl[2][128 * 32];
    const int m0 = blockIdx.x * 128;
    const int n0 = blockIdx.y * 128;
    const int tid = threadIdx.x;
    const int wid = tid >> 6, lane = tid & 63;
    const int ln = lane & 15, q = lane >> 4;
    const int qs8 = (q ^ ((ln >> 1) & 3)) * 8;          // swizzled read chunk
    const int wm = (wid >> 1) * 64, wn = (wid & 1) * 64;
    const int srow = tid >> 2;
    const int spart = (tid & 3) ^ ((srow >> 1) & 3);    // swizzled src chunk

    const u16* gA0 = &A[(size_t)(m0 + srow) * 256 + spart * 8];
    const u16* gB0 = &Bt[(size_t)(n0 + srow) * 256 + spart * 8];

#define STG(b, kk) do {                                                     \
        gl16(gA0 + (kk) * 32,            &Al[b][wid * 512]);                \
        gl16(gA0 + 64 * 256 + (kk) * 32, &Al[b][2048 + wid * 512]);         \
        gl16(gB0 + (kk) * 32,            &Bl[b][wid * 512]);                \
        gl16(gB0 + 64 * 256 + (kk) * 32, &Bl[b][2048 + wid * 512]);         \
    } while (0)

    v4f acc[4][4] = {};
    STG(0, 0);
    __syncthreads();
#pragma unroll
    for (int kt = 0; kt < 8; ++kt) {
        const int cb = kt & 1, nb = cb ^ 1;
        if (kt < 7) STG(nb, kt + 1);
        v8s af[4], bfv[4];
#pragma unroll
        for (int i = 0; i < 4; ++i)
            af[i] = *(const v8s*)&Al[cb][(wm + i * 16 + ln) * 32 + qs8];
#pragma unroll
        for (int j = 0; j < 4; ++j)
            bfv[j] = *(const v8s*)&Bl[cb][(wn + j * 16 + ln) * 32 + qs8];
#pragma unroll
        for (int i = 0; i < 4; ++i)
#pragma unroll
            for (int j = 0; j < 4; ++j)
                acc[i][j] = __builtin_amdgcn_mfma_f32_16x16x32_bf16(
                    af[i], bfv[j], acc[i][j], 0, 0, 0);
        __syncthreads();
    }
#undef STG
#pragma unroll
    for (int i = 0; i < 4; ++i)
#pragma unroll
        for (int j = 0; j < 4; ++j) {
            int gc = n0 + wn + j * 16 + ln;
            float b = bias[gc];
#pragma unroll
            for (int r = 0; r < 4; ++r) {
                int gr = m0 + wm + i * 16 + q * 4 + r;
                float v = acc[i][j][r] + b;
                if (ACT) v = v > 0.f ? v : 0.1f * v;
                C[(size_t)gr * nc + gc] = f2bf(v);
            }
        }
}

// ---------------------------------------------------------------------------
// Graph mix: msg[(n,w),c] = sum_{k,v} y[(n,v),k*256+c] * aadj[k][v][w]
// ---------------------------------------------------------------------------
__global__ __launch_bounds__(256) void graph_mix(
    const u16* __restrict__ y, const float* __restrict__ aadj,
    u16* __restrict__ msg)
{
    __shared__ u16 yl[VN * 768];
    const int n = blockIdx.x, tid = threadIdx.x;
    const uint4* src = (const uint4*)(y + (size_t)n * VN * 768);
    for (int idx = tid; idx < VN * 768 / 8; idx += 256)
        ((uint4*)yl)[idx] = src[idx];
    __syncthreads();
    const int c = tid;
    float acc[VN] = {};
    for (int k = 0; k < KNUM; ++k)
        for (int v = 0; v < VN; ++v) {
            float yv = bf2f(yl[v * 768 + k * 256 + c]);
            const float* ap = &aadj[(k * VN + v) * VN];
#pragma unroll
            for (int w = 0; w < VN; ++w) acc[w] += yv * ap[w];
        }
    size_t base = (size_t)n * VN * 256;
    for (int w = 0; w < VN; ++w) msg[base + w * 256 + c] = f2bf(acc[w]);
}

// ---------------------------------------------------------------------------
// Fused GRU, K=288: cols 0..255 = msg (Wh*), 256..287 = xpad (x-proj + bias).
// BYTE-EXACT R0 structure (117 us @ 19.5% occupancy, VGPR 116): rolled kt
// loop (NO unroll pragma — R2's unroll cost 140 VGPR / 11% occupancy / 196us),
// single LDS buffer, two barriers per K-step, inline ternary addressing.
// Only change vs R0: constant-folded XOR swizzle (spart / qs8) -> bank
// conflicts 4.9M -> 0 at zero addressing cost.
// grid = (832, 4); block = 128 rows x 64 cols x 3 gates.
// ---------------------------------------------------------------------------
__global__ __launch_bounds__(256) void gru_fused(
    const u16* __restrict__ Am, const u16* __restrict__ xpad,
    const u16* __restrict__ hprev, u16* __restrict__ hout,
    const u16* __restrict__ wfull, const u16* __restrict__ wxn)
{
    __shared__ u16 Al[128 * 32];   // 8 KB
    __shared__ u16 Bl[192 * 32];   // 12 KB
    __shared__ u16 Xl[64 * 32];    // 4 KB
    const int m0 = blockIdx.x * 128;
    const int n0 = blockIdx.y * 64;
    const int tid = threadIdx.x;
    const int wid = tid >> 6, lane = tid & 63;
    const int ln = lane & 15, q = lane >> 4;
    const int qs8 = (q ^ ((ln >> 1) & 3)) * 8;
    const int wm = (wid >> 1) * 64, wn = (wid & 1) * 32;
    const int srow = tid >> 2;
    const int spart = (tid & 3) ^ ((srow >> 1) & 3);

    // wxn tile (64 rows of this block's n0 slice), needed only at kt==8
    gl16(&wxn[(size_t)(n0 + srow) * 32 + spart * 8], &Xl[(wid * 64) * 8]);

    v4f accr[4][2] = {}, accz[4][2] = {}, acch[4][2] = {}, accn[4][2] = {};

    for (int kt = 0; kt < 9; ++kt) {
#pragma unroll
        for (int p = 0; p < 2; ++p) {
            const u16* ga = (kt < 8)
                ? &Am[(size_t)(m0 + p * 64 + srow) * 256 + kt * 32 + spart * 8]
                : &xpad[(size_t)(m0 + p * 64 + srow) * 32 + spart * 8];
            gl16(ga, &Al[(p * 256 + wid * 64) * 8]);
        }
#pragma unroll
        for (int p = 0; p < 3; ++p)
            gl16(&wfull[(size_t)(p * 256 + n0 + srow) * 288 + kt * 32 + spart * 8],
                 &Bl[(p * 256 + wid * 64) * 8]);
        __syncthreads();

        v8s af[4];
#pragma unroll
        for (int i = 0; i < 4; ++i)
            af[i] = *(const v8s*)&Al[(wm + i * 16 + ln) * 32 + qs8];
        v8s bfr[3][2];
#pragma unroll
        for (int g = 0; g < 3; ++g)
#pragma unroll
            for (int j = 0; j < 2; ++j)
                bfr[g][j] = *(const v8s*)&Bl[(g * 64 + wn + j * 16 + ln) * 32 + qs8];
#pragma unroll
        for (int i = 0; i < 4; ++i)
#pragma unroll
            for (int j = 0; j < 2; ++j) {
                accr[i][j] = __builtin_amdgcn_mfma_f32_16x16x32_bf16(af[i], bfr[0][j], accr[i][j], 0, 0, 0);
                accz[i][j] = __builtin_amdgcn_mfma_f32_16x16x32_bf16(af[i], bfr[1][j], accz[i][j], 0, 0, 0);
                acch[i][j] = __builtin_amdgcn_mfma_f32_16x16x32_bf16(af[i], bfr[2][j], acch[i][j], 0, 0, 0);
            }
        if (kt == 8) {
            v8s bfn[2];
#pragma unroll
            for (int j = 0; j < 2; ++j)
                bfn[j] = *(const v8s*)&Xl[(wn + j * 16 + ln) * 32 + qs8];
#pragma unroll
            for (int i = 0; i < 4; ++i)
#pragma unroll
                for (int j = 0; j < 2; ++j)
                    accn[i][j] = __builtin_amdgcn_mfma_f32_16x16x32_bf16(af[i], bfn[j], accn[i][j], 0, 0, 0);
        }
        __syncthreads();
    }

#pragma unroll
    for (int i = 0; i < 4; ++i)
#pragma unroll
        for (int j = 0; j < 2; ++j) {
            int gc = n0 + wn + j * 16 + ln;
#pragma unroll
            for (int r = 0; r < 4; ++r) {
                int gr = m0 + wm + i * 16 + q * 4 + r;
                float rg = sigm(accr[i][j][r]);
                float zg = sigm(accz[i][j][r]);
                float nn = tanh_fast(accn[i][j][r] + rg * acch[i][j][r]);
                float hp = bf2f(hprev[(size_t)gr * 256 + gc]);
                hout[(size_t)gr * 256 + gc] = f2bf((1.f - zg) * nn + zg * hp);
            }
        }
}

// ---------------------------------------------------------------------------
// Head: res = hd2 @ W3^T + b3 ; pred = h1 + res ; write out[:, s], pnew,
// and next step's xpad row [pred, h2'-h3', pred-2h2'+h3', 1, 0...].
// ---------------------------------------------------------------------------
__global__ __launch_bounds__(256) void head_out(
    const u16* __restrict__ hd2, const float* __restrict__ w3,
    const float* __restrict__ b3, const float* __restrict__ p1,
    const float* __restrict__ p2, float* __restrict__ pnew,
    u16* __restrict__ xpad, float* __restrict__ out, int s)
{
    __shared__ u16 hl[32 * 256];
    __shared__ float w3l[3 * 256];
    const int bm = blockIdx.x, tid = threadIdx.x;
    const uint4* src = (const uint4*)(hd2 + (size_t)bm * 32 * 256);
    for (int idx = tid; idx < 1024; idx += 256) ((uint4*)hl)[idx] = src[idx];
    for (int idx = tid; idx < 768; idx += 256) w3l[idx] = w3[idx];
    __syncthreads();
    const int r = tid >> 3, l8 = tid & 7;
    float s0 = 0.f, s1 = 0.f, s2 = 0.f;
    for (int c = l8 * 32; c < l8 * 32 + 32; ++c) {
        float hv = bf2f(hl[r * 256 + c]);
        s0 += hv * w3l[c];
        s1 += hv * w3l[256 + c];
        s2 += hv * w3l[512 + c];
    }
    for (int off = 1; off < 8; off <<= 1) {
        s0 += __shfl_xor(s0, off, 8);
        s1 += __shfl_xor(s1, off, 8);
        s2 += __shfl_xor(s2, off, 8);
    }
    // butterfly leaves the full sums in ALL 8 lanes
    const int m = bm * 32 + r;
    float a0 = p1[m * 3 + 0], a1 = p1[m * 3 + 1], a2 = p1[m * 3 + 2];
    float c0 = p2[m * 3 + 0], c1 = p2[m * 3 + 1], c2 = p2[m * 3 + 2];
    float o0 = a0 + s0 + b3[0];
    float o1 = a1 + s1 + b3[1];
    float o2 = a2 + s2 + b3[2];
    if (l8 == 0) {
        size_t ob = ((size_t)m * TS + s) * 3;
        out[ob + 0] = o0; out[ob + 1] = o1; out[ob + 2] = o2;
        pnew[m * 3 + 0] = o0; pnew[m * 3 + 1] = o1; pnew[m * 3 + 2] = o2;
    }
    // next x: ins_p=pred, ins_v=p1-p2, ins_a=pred-2*p1+p2, col9=1, rest 0
    u16 xv[4];
#pragma unroll
    for (int t = 0; t < 4; ++t) {
        int c = l8 * 4 + t;
        float v = 0.f;
        if (c == 0) v = o0; else if (c == 1) v = o1; else if (c == 2) v = o2;
        else if (c == 3) v = a0 - c0; else if (c == 4) v = a1 - c1;
        else if (c == 5) v = a2 - c2;
        else if (c == 6) v = o0 - 2.f * a0 + c0;
        else if (c == 7) v = o1 - 2.f * a1 + c1;
        else if (c == 8) v = o2 - 2.f * a2 + c2;
        else if (c == 9) v = 1.f;
        xv[t] = f2bf(v);
    }
    uint2 pk;
    pk.x = (unsigned)xv[0] | ((unsigned)xv[1] << 16);
    pk.y = (unsigned)xv[2] | ((unsigned)xv[3] << 16);
    ((uint2*)&xpad[(size_t)m * 32])[l8] = pk;
}

// ---------------------------------------------------------------------------
// Step-0 xpad from the three input frames.
// ---------------------------------------------------------------------------
__global__ __launch_bounds__(256) void init_xpad(
    const float* __restrict__ x0, const float* __restrict__ xp,
    const float* __restrict__ xp2, u16* __restrict__ xpad)
{
    int m = blockIdx.x * 256 + threadIdx.x;
    float a0 = x0[m * 3 + 0], a1 = x0[m * 3 + 1], a2 = x0[m * 3 + 2];
    float b0 = xp[m * 3 + 0], b1 = xp[m * 3 + 1], b2 = xp[m * 3 + 2];
    float c0 = xp2[m * 3 + 0], c1 = xp2[m * 3 + 1], c2 = xp2[m * 3 + 2];
    unsigned t[32];
#pragma unroll
    for (int i = 0; i < 32; ++i) t[i] = 0;
    t[0] = f2bf(a0); t[1] = f2bf(a1); t[2] = f2bf(a2);
    t[3] = f2bf(b0 - c0); t[4] = f2bf(b1 - c1); t[5] = f2bf(b2 - c2);
    t[6] = f2bf(a0 - 2.f * b0 + c0);
    t[7] = f2bf(a1 - 2.f * b1 + c1);
    t[8] = f2bf(a2 - 2.f * b2 + c2);
    t[9] = f2bf(1.f);
    uint4* dst = (uint4*)&xpad[(size_t)m * 32];
#pragma unroll
    for (int wq = 0; wq < 4; ++wq) {
        uint4 u;
        u.x = t[wq * 8 + 0] | (t[wq * 8 + 1] << 16);
        u.y = t[wq * 8 + 2] | (t[wq * 8 + 3] << 16);
        u.z = t[wq * 8 + 4] | (t[wq * 8 + 5] << 16);
        u.w = t[wq * 8 + 6] | (t[wq * 8 + 7] << 16);
        dst[wq] = u;
    }
}

// ---------------------------------------------------------------------------
// hidden [N,C,V] fp32 -> h[(n,v),c] bf16.
// ---------------------------------------------------------------------------
__global__ __launch_bounds__(256) void transpose_h(
    const float* __restrict__ hidden, u16* __restrict__ hA)
{
    __shared__ float hl[256 * VN];
    const int n = blockIdx.x, tid = threadIdx.x;
    const uint4* src = (const uint4*)(hidden + (size_t)n * 256 * VN);
    for (int idx = tid; idx < 256 * VN / 4; idx += 256)
        ((uint4*)hl)[idx] = src[idx];
    __syncthreads();
    size_t base = (size_t)n * VN * 256;
    for (int idx = tid; idx < VN * 256; idx += 256) {
        int v = idx >> 8, c = idx & 255;
        hA[base + idx] = f2bf(hl[c * VN + v]);
    }
}

// ---------------------------------------------------------------------------
// Weight packing (once per call).
// wfull[768,288]: row g*256+c -> cols 0..255 = Wh_g[c,:],
//   256..264 = x-weights (g<2), 265 = bias (g<2), rest 0.
// wxn[256,32]:   row c -> 0..8 = Win[c,:], 9 = b_in[c], rest 0.
// ---------------------------------------------------------------------------
__global__ __launch_bounds__(256) void pack_weights(
    const float* __restrict__ Whr, const float* __restrict__ Whi,
    const float* __restrict__ Whh, const float* __restrict__ convw_f,
    const float* __restrict__ W1f, const float* __restrict__ W2f,
    const float* __restrict__ Af, const float* __restrict__ emul,
    const float* __restrict__ eadd, const float* __restrict__ Wir,
    const float* __restrict__ Wii, const float* __restrict__ Win,
    const float* __restrict__ bir, const float* __restrict__ bii,
    const float* __restrict__ b_in, const float* __restrict__ convb_f,
    const float* __restrict__ b1f, const float* __restrict__ b2f,
    const float* __restrict__ W3f, const float* __restrict__ b3f,
    u16* __restrict__ wfull, u16* __restrict__ wxn, u16* __restrict__ convw,
    u16* __restrict__ w1, u16* __restrict__ w2, float* __restrict__ aadj,
    float* __restrict__ convb, float* __restrict__ b1, float* __restrict__ b2,
    float* __restrict__ w3, float* __restrict__ b3)
{
    int gid = blockIdx.x * 256 + threadIdx.x;
    int stride = gridDim.x * 256;
    for (int i = gid; i < 768 * 288; i += stride) {
        int row = i / 288, col = i - row * 288;
        int g = row >> 8, c = row & 255;
        float v = 0.f;
        if (col < 256)
            v = (g == 0 ? Whr : (g == 1 ? Whi : Whh))[c * 256 + col];
        else if (col < 265) {
            int tcol = col - 256;
            v = (g == 0 ? Wir[c * 9 + tcol] : (g == 1 ? Wii[c * 9 + tcol] : 0.f));
        } else if (col == 265)
            v = (g == 0 ? bir[c] : (g == 1 ? bii[c] : 0.f));
        wfull[i] = f2bf(v);
    }
    for (int i = gid; i < 256 * 32; i += stride) {
        int c = i >> 5, col = i & 31;
        float v = 0.f;
        if (col < 9) v = Win[c * 9 + col];
        else if (col == 9) v = b_in[c];
        wxn[i] = f2bf(v);
    }
    for (int i = gid; i < 65536; i += stride) {
        w1[i] = f2bf(W1f[i]);
        w2[i] = f2bf(W2f[i]);
    }
    for (int i = gid; i < 196608; i += stride) convw[i] = f2bf(convw_f[i]);
    for (int i = gid; i < KNUM * VN * VN; i += stride)
        aadj[i] = Af[i] * emul[i] + eadd[i];
    for (int i = gid; i < 256; i += stride) { b1[i] = b1f[i]; b2[i] = b2f[i]; }
    for (int i = gid; i < 768; i += stride) { convb[i] = convb_f[i]; w3[i] = W3f[i]; }
    if (gid < 3) b3[gid] = b3f[gid];
}

// ---------------------------------------------------------------------------
extern "C" void kernel_launch(void* const* d_in, const int* in_sizes, int n_in,
                              void* d_out, int out_size, void* d_ws, size_t ws_size,
                              hipStream_t stream)
{
    const float* inputs   = (const float*)d_in[0];
    const float* inputs_p = (const float*)d_in[1];
    const float* inputs_p2= (const float*)d_in[2];
    const float* hidden   = (const float*)d_in[3];
    const float* Af       = (const float*)d_in[4];
    const float* emul     = (const float*)d_in[5];
    const float* eadd     = (const float*)d_in[6];
    const float* conv_w   = (const float*)d_in[7];
    const float* conv_b   = (const float*)d_in[8];
    const float* Wir      = (const float*)d_in[9];
    const float* bir      = (const float*)d_in[10];
    const float* Wii      = (const float*)d_in[11];
    const float* bii      = (const float*)d_in[12];
    const float* Win      = (const float*)d_in[13];
    const float* b_in     = (const float*)d_in[14];
    const float* Whr      = (const float*)d_in[15];
    const float* Whi      = (const float*)d_in[16];
    const float* Whh      = (const float*)d_in[17];
    const float* W1f      = (const float*)d_in[18];
    const float* b1f      = (const float*)d_in[19];
    const float* W2f      = (const float*)d_in[20];
    const float* b2f      = (const float*)d_in[21];
    const float* W3f      = (const float*)d_in[22];
    const float* b3f      = (const float*)d_in[23];
    float* out = (float*)d_out;

    const size_t M = M_ROWS;
    char* ws = (char*)d_ws;
    size_t off = 0;
    auto alloc = [&](size_t bytes) -> void* {
        void* p = ws + off;
        off = (off + bytes + 255) & ~(size_t)255;
        return p;
    };
    u16* hA    = (u16*)alloc(M * 256 * 2);
    u16* hB    = (u16*)alloc(M * 256 * 2);
    u16* msg   = (u16*)alloc(M * 256 * 2);
    u16* ybuf  = (u16*)alloc(M * 768 * 2);
    u16* xpad  = (u16*)alloc(M * 32 * 2);
    float* pa  = (float*)alloc(M * 3 * 4);
    float* pb  = (float*)alloc(M * 3 * 4);
    float* pc  = (float*)alloc(M * 3 * 4);
    u16* wfull = (u16*)alloc(768 * 288 * 2);
    u16* wxn   = (u16*)alloc(256 * 32 * 2);
    u16* convw = (u16*)alloc(196608 * 2);
    u16* w1    = (u16*)alloc(65536 * 2);
    u16* w2    = (u16*)alloc(65536 * 2);
    float* aadj  = (float*)alloc(KNUM * VN * VN * 4);
    float* convb = (float*)alloc(768 * 4);
    float* b1    = (float*)alloc(256 * 4);
    float* b2    = (float*)alloc(256 * 4);
    float* w3    = (float*)alloc(768 * 4);
    float* b3    = (float*)alloc(16);
    if (off > ws_size) return;

    pack_weights<<<512, 256, 0, stream>>>(
        Whr, Whi, Whh, conv_w, W1f, W2f, Af, emul, eadd, Wir, Wii, Win,
        bir, bii, b_in, conv_b, b1f, b2f, W3f, b3f,
        wfull, wxn, convw, w1, w2, aadj, convb, b1, b2, w3, b3);
    transpose_h<<<NBATCH, 256, 0, stream>>>(hidden, hA);
    init_xpad<<<M_ROWS / 256, 256, 0, stream>>>(inputs, inputs_p, inputs_p2, xpad);
    hipMemcpyAsync(pa, inputs,    M * 3 * 4, hipMemcpyDeviceToDevice, stream);
    hipMemcpyAsync(pb, inputs_p,  M * 3 * 4, hipMemcpyDeviceToDevice, stream);
    hipMemcpyAsync(pc, inputs_p2, M * 3 * 4, hipMemcpyDeviceToDevice, stream);

    u16* hcur = hA;  u16* hnext = hB;
    float* P1 = pa;  float* P2 = pb;  float* P3 = pc;
    u16* hd  = ybuf;
    u16* hd2 = ybuf + M * 256;
    const int MB = M_ROWS / 128;  // 832

    for (int s = 0; s < TS; ++s) {
        const u16* m_ptr;
        if (s < 10) {
            gemm_nt<0><<<dim3(MB, 6), 256, 0, stream>>>(hcur, convw, convb, ybuf, 768);
            graph_mix<<<NBATCH, 256, 0, stream>>>(ybuf, aadj, msg);
            m_ptr = msg;
        } else {
            m_ptr = hcur;
        }
        gru_fused<<<dim3(MB, 4), 256, 0, stream>>>(m_ptr, xpad, hcur, hnext,
                                                   wfull, wxn);
        gemm_nt<1><<<dim3(MB, 2), 256, 0, stream>>>(hnext, w1, b1, hd, 256);
        gemm_nt<1><<<dim3(MB, 2), 256, 0, stream>>>(hd, w2, b2, hd2, 256);
        // head also emits xpad for step s+1
        head_out<<<M_ROWS / 32, 256, 0, stream>>>(hd2, w3, b3, P1, P2, P3,
                                                  xpad, out, s);
        float* t = P3; P3 = P2; P2 = P1; P1 = t;
        u16* ht = hcur; hcur = hnext; hnext = ht;
    }
}

// Round 4
// 6412.427 us; speedup vs baseline: 1.2996x; 1.0833x over previous
//
#include <hip/hip_runtime.h>

// Problem constants (fixed by the reference)
#define M_ROWS 106496   // 4096*26  (n,v) rows
#define NBATCH 4096
#define VN 26
#define KNUM 3
#define TS 25

typedef unsigned short u16;
typedef __attribute__((ext_vector_type(8))) short v8s;
typedef __attribute__((ext_vector_type(4))) float v4f;

__device__ __forceinline__ u16 f2bf(float f) {
    unsigned u = __float_as_uint(f);
    u += 0x7FFF + ((u >> 16) & 1);   // RNE
    return (u16)(u >> 16);
}
__device__ __forceinline__ float bf2f(u16 h) {
    return __uint_as_float(((unsigned)h) << 16);
}
__device__ __forceinline__ float sigm(float x) {
    return 1.f / (1.f + __expf(-x));
}
__device__ __forceinline__ float tanh_fast(float x) {
    return 2.f / (1.f + __expf(-2.f * x)) - 1.f;
}

// Async global->LDS, 16B per lane. LDS dest must be the wave-uniform base;
// HW adds lane*16. Staging layout stays LINEAR in lane order; the LDS
// swizzle is realized by pre-permuting the per-lane GLOBAL source chunk
// (rule: both-sides-or-neither with global_load_lds).
typedef const __attribute__((address_space(1))) unsigned int* gas_t;
typedef __attribute__((address_space(3))) unsigned int* las_t;
__device__ __forceinline__ void gl16(const void* g, void* l) {
    __builtin_amdgcn_global_load_lds((gas_t)g, (las_t)l, 16, 0, 0);
}

// ---------------------------------------------------------------------------
// Generic NT gemm: C[M,nc] = A[M,256](bf16) @ Bt[nc,256](bf16)^T + bias
// BM=128, BN=128, BK=32; 256 threads = 4 waves (2x2), each wave 64x64.
// 2-phase double-buffered pipeline (MEASURED faster for this kernel in R1:
// non-gru time 4131 -> ~3200-3400 us). LDS chunk-XOR swizzle kills the
// ds_read_b128 bank conflicts. DO NOT TOUCH without an A/B.
// ACT=0: bias only. ACT=1: bias + leaky_relu(0.1).
// ---------------------------------------------------------------------------
template <int ACT>
__global__ __launch_bounds__(256) void gemm_nt(
    const u16* __restrict__ A, const u16* __restrict__ Bt,
    const float* __restrict__ bias, u16* __restrict__ C, int nc)
{
    __shared__ u16 Al[2][128 * 32];
    __shared__ u16 Bl[2][128 * 32];
    const int m0 = blockIdx.x * 128;
    const int n0 = blockIdx.y * 128;
    const int tid = threadIdx.x;
    const int wid = tid >> 6, lane = tid & 63;
    const int ln = lane & 15, q = lane >> 4;
    const int qs8 = (q ^ ((ln >> 1) & 3)) * 8;          // swizzled read chunk
    const int wm = (wid >> 1) * 64, wn = (wid & 1) * 64;
    const int srow = tid >> 2;
    const int spart = (tid & 3) ^ ((srow >> 1) & 3);    // swizzled src chunk

    const u16* gA0 = &A[(size_t)(m0 + srow) * 256 + spart * 8];
    const u16* gB0 = &Bt[(size_t)(n0 + srow) * 256 + spart * 8];

#define STG(b, kk) do {                                                     \
        gl16(gA0 + (kk) * 32,            &Al[b][wid * 512]);                \
        gl16(gA0 + 64 * 256 + (kk) * 32, &Al[b][2048 + wid * 512]);         \
        gl16(gB0 + (kk) * 32,            &Bl[b][wid * 512]);                \
        gl16(gB0 + 64 * 256 + (kk) * 32, &Bl[b][2048 + wid * 512]);         \
    } while (0)

    v4f acc[4][4] = {};
    STG(0, 0);
    __syncthreads();
#pragma unroll
    for (int kt = 0; kt < 8; ++kt) {
        const int cb = kt & 1, nb = cb ^ 1;
        if (kt < 7) STG(nb, kt + 1);
        v8s af[4], bfv[4];
#pragma unroll
        for (int i = 0; i < 4; ++i)
            af[i] = *(const v8s*)&Al[cb][(wm + i * 16 + ln) * 32 + qs8];
#pragma unroll
        for (int j = 0; j < 4; ++j)
            bfv[j] = *(const v8s*)&Bl[cb][(wn + j * 16 + ln) * 32 + qs8];
#pragma unroll
        for (int i = 0; i < 4; ++i)
#pragma unroll
            for (int j = 0; j < 4; ++j)
                acc[i][j] = __builtin_amdgcn_mfma_f32_16x16x32_bf16(
                    af[i], bfv[j], acc[i][j], 0, 0, 0);
        __syncthreads();
    }
#undef STG
#pragma unroll
    for (int i = 0; i < 4; ++i)
#pragma unroll
        for (int j = 0; j < 4; ++j) {
            int gc = n0 + wn + j * 16 + ln;
            float b = bias[gc];
#pragma unroll
            for (int r = 0; r < 4; ++r) {
                int gr = m0 + wm + i * 16 + q * 4 + r;
                float v = acc[i][j][r] + b;
                if (ACT) v = v > 0.f ? v : 0.1f * v;
                C[(size_t)gr * nc + gc] = f2bf(v);
            }
        }
}

// ---------------------------------------------------------------------------
// Fused W2-gemm + W3 head projection.
// hd2 = leaky(hd @ W2^T + b2) computed in registers (NEVER written to HBM);
// per-block partial res[row][t] = sum_{cols in block} hd2 * w3[t][col]
// via 16-lane butterfly + LDS cross-wave combine -> resp[by] (2.6 MB).
// head_fin sums the two column-block partials.
// Same dbuf+swizzle main loop as gemm_nt (measured-good). grid (832, 2).
// ---------------------------------------------------------------------------
__global__ __launch_bounds__(256) void gemm_head(
    const u16* __restrict__ A, const u16* __restrict__ Bt,
    const float* __restrict__ bias, const float* __restrict__ w3,
    float* __restrict__ resp0, float* __restrict__ resp1)
{
    __shared__ u16 Al[2][128 * 32];
    __shared__ u16 Bl[2][128 * 32];
    __shared__ float w3l[3 * 128];
    __shared__ float resl[2][128][3];
    const int m0 = blockIdx.x * 128;
    const int by = blockIdx.y;
    const int n0 = by * 128;
    const int tid = threadIdx.x;
    const int wid = tid >> 6, lane = tid & 63;
    const int ln = lane & 15, q = lane >> 4;
    const int qs8 = (q ^ ((ln >> 1) & 3)) * 8;
    const int wm = (wid >> 1) * 64, wn = (wid & 1) * 64;
    const int wnh = wid & 1;
    const int srow = tid >> 2;
    const int spart = (tid & 3) ^ ((srow >> 1) & 3);

    // stage this block's w3 columns: w3l[t*128 + c] = w3[t*256 + n0 + c]
    for (int idx = tid; idx < 384; idx += 256)
        w3l[idx] = w3[(idx >> 7) * 256 + n0 + (idx & 127)];

    const u16* gA0 = &A[(size_t)(m0 + srow) * 256 + spart * 8];
    const u16* gB0 = &Bt[(size_t)(n0 + srow) * 256 + spart * 8];

#define STG(b, kk) do {                                                     \
        gl16(gA0 + (kk) * 32,            &Al[b][wid * 512]);                \
        gl16(gA0 + 64 * 256 + (kk) * 32, &Al[b][2048 + wid * 512]);         \
        gl16(gB0 + (kk) * 32,            &Bl[b][wid * 512]);                \
        gl16(gB0 + 64 * 256 + (kk) * 32, &Bl[b][2048 + wid * 512]);         \
    } while (0)

    v4f acc[4][4] = {};
    STG(0, 0);
    __syncthreads();
#pragma unroll
    for (int kt = 0; kt < 8; ++kt) {
        const int cb = kt & 1, nb = cb ^ 1;
        if (kt < 7) STG(nb, kt + 1);
        v8s af[4], bfv[4];
#pragma unroll
        for (int i = 0; i < 4; ++i)
            af[i] = *(const v8s*)&Al[cb][(wm + i * 16 + ln) * 32 + qs8];
#pragma unroll
        for (int j = 0; j < 4; ++j)
            bfv[j] = *(const v8s*)&Bl[cb][(wn + j * 16 + ln) * 32 + qs8];
#pragma unroll
        for (int i = 0; i < 4; ++i)
#pragma unroll
            for (int j = 0; j < 4; ++j)
                acc[i][j] = __builtin_amdgcn_mfma_f32_16x16x32_bf16(
                    af[i], bfv[j], acc[i][j], 0, 0, 0);
        __syncthreads();
    }
#undef STG

    // epilogue: leaky + W3 partial dot, reduced across the 16 ln-lanes
    float bj[4], wv[3][4];
#pragma unroll
    for (int j = 0; j < 4; ++j) {
        bj[j] = bias[n0 + wn + j * 16 + ln];
#pragma unroll
        for (int t = 0; t < 3; ++t)
            wv[t][j] = w3l[t * 128 + wn + j * 16 + ln];
    }
#pragma unroll
    for (int i = 0; i < 4; ++i) {
        float part[3][4] = {};
#pragma unroll
        for (int j = 0; j < 4; ++j)
#pragma unroll
            for (int r = 0; r < 4; ++r) {
                float v = acc[i][j][r] + bj[j];
                v = v > 0.f ? v : 0.1f * v;
                part[0][r] += v * wv[0][j];
                part[1][r] += v * wv[1][j];
                part[2][r] += v * wv[2][j];
            }
#pragma unroll
        for (int off = 1; off < 16; off <<= 1)
#pragma unroll
            for (int t = 0; t < 3; ++t)
#pragma unroll
                for (int r = 0; r < 4; ++r)
                    part[t][r] += __shfl_xor(part[t][r], off, 16);
        if (ln == 0) {
            int row = wm + i * 16 + q * 4;
#pragma unroll
            for (int r = 0; r < 4; ++r)
#pragma unroll
                for (int t = 0; t < 3; ++t)
                    resl[wnh][row + r][t] = part[t][r];
        }
    }
    __syncthreads();
    float* rp = by ? resp1 : resp0;
    for (int idx = tid; idx < 384; idx += 256) {
        int t = idx >> 7, row = idx & 127;
        rp[(size_t)(m0 + row) * 3 + t] = resl[0][row][t] + resl[1][row][t];
    }
}

// ---------------------------------------------------------------------------
// Head finisher: res = resp0 + resp1 + b3 ; pred = p1 + res ; writes out[:,s],
// pnew, and next step's xpad row. Tiny (~8 MB traffic).
// ---------------------------------------------------------------------------
__global__ __launch_bounds__(256) void head_fin(
    const float* __restrict__ resp0, const float* __restrict__ resp1,
    const float* __restrict__ b3, const float* __restrict__ p1,
    const float* __restrict__ p2, float* __restrict__ pnew,
    u16* __restrict__ xpad, float* __restrict__ out, int s)
{
    int m = blockIdx.x * 256 + threadIdx.x;
    float s0 = resp0[m * 3 + 0] + resp1[m * 3 + 0];
    float s1 = resp0[m * 3 + 1] + resp1[m * 3 + 1];
    float s2 = resp0[m * 3 + 2] + resp1[m * 3 + 2];
    float a0 = p1[m * 3 + 0], a1 = p1[m * 3 + 1], a2 = p1[m * 3 + 2];
    float c0 = p2[m * 3 + 0], c1 = p2[m * 3 + 1], c2 = p2[m * 3 + 2];
    float o0 = a0 + s0 + b3[0];
    float o1 = a1 + s1 + b3[1];
    float o2 = a2 + s2 + b3[2];
    size_t ob = ((size_t)m * TS + s) * 3;
    out[ob + 0] = o0; out[ob + 1] = o1; out[ob + 2] = o2;
    pnew[m * 3 + 0] = o0; pnew[m * 3 + 1] = o1; pnew[m * 3 + 2] = o2;
    unsigned t[32];
#pragma unroll
    for (int i = 0; i < 32; ++i) t[i] = 0;
    t[0] = f2bf(o0); t[1] = f2bf(o1); t[2] = f2bf(o2);
    t[3] = f2bf(a0 - c0); t[4] = f2bf(a1 - c1); t[5] = f2bf(a2 - c2);
    t[6] = f2bf(o0 - 2.f * a0 + c0);
    t[7] = f2bf(o1 - 2.f * a1 + c1);
    t[8] = f2bf(o2 - 2.f * a2 + c2);
    t[9] = f2bf(1.f);
    uint4* dst = (uint4*)&xpad[(size_t)m * 32];
#pragma unroll
    for (int wq = 0; wq < 4; ++wq) {
        uint4 u;
        u.x = t[wq * 8 + 0] | (t[wq * 8 + 1] << 16);
        u.y = t[wq * 8 + 2] | (t[wq * 8 + 3] << 16);
        u.z = t[wq * 8 + 4] | (t[wq * 8 + 5] << 16);
        u.w = t[wq * 8 + 6] | (t[wq * 8 + 7] << 16);
        dst[wq] = u;
    }
}

// ---------------------------------------------------------------------------
// Graph mix: msg[(n,w),c] = sum_{k,v} y[(n,v),k*256+c] * aadj[k][v][w]
// ---------------------------------------------------------------------------
__global__ __launch_bounds__(256) void graph_mix(
    const u16* __restrict__ y, const float* __restrict__ aadj,
    u16* __restrict__ msg)
{
    __shared__ u16 yl[VN * 768];
    const int n = blockIdx.x, tid = threadIdx.x;
    const uint4* src = (const uint4*)(y + (size_t)n * VN * 768);
    for (int idx = tid; idx < VN * 768 / 8; idx += 256)
        ((uint4*)yl)[idx] = src[idx];
    __syncthreads();
    const int c = tid;
    float acc[VN] = {};
    for (int k = 0; k < KNUM; ++k)
        for (int v = 0; v < VN; ++v) {
            float yv = bf2f(yl[v * 768 + k * 256 + c]);
            const float* ap = &aadj[(k * VN + v) * VN];
#pragma unroll
            for (int w = 0; w < VN; ++w) acc[w] += yv * ap[w];
        }
    size_t base = (size_t)n * VN * 256;
    for (int w = 0; w < VN; ++w) msg[base + w * 256 + c] = f2bf(acc[w]);
}

// ---------------------------------------------------------------------------
// Fused GRU, K=288: cols 0..255 = msg (Wh*), 256..287 = xpad (x-proj + bias).
// BYTE-EXACT R0 structure (117 us @ 19.5% occupancy, VGPR 116): rolled kt
// loop (NO unroll pragma — R2's unroll cost 140 VGPR / 11% occupancy / 196us),
// single LDS buffer, two barriers per K-step, inline ternary addressing.
// Only change vs R0: constant-folded XOR swizzle (spart / qs8) -> bank
// conflicts 4.9M -> 0 at zero addressing cost. Measured 115.5 us (R3).
// grid = (832, 4); block = 128 rows x 64 cols x 3 gates. DO NOT TOUCH.
// ---------------------------------------------------------------------------
__global__ __launch_bounds__(256) void gru_fused(
    const u16* __restrict__ Am, const u16* __restrict__ xpad,
    const u16* __restrict__ hprev, u16* __restrict__ hout,
    const u16* __restrict__ wfull, const u16* __restrict__ wxn)
{
    __shared__ u16 Al[128 * 32];   // 8 KB
    __shared__ u16 Bl[192 * 32];   // 12 KB
    __shared__ u16 Xl[64 * 32];    // 4 KB
    const int m0 = blockIdx.x * 128;
    const int n0 = blockIdx.y * 64;
    const int tid = threadIdx.x;
    const int wid = tid >> 6, lane = tid & 63;
    const int ln = lane & 15, q = lane >> 4;
    const int qs8 = (q ^ ((ln >> 1) & 3)) * 8;
    const int wm = (wid >> 1) * 64, wn = (wid & 1) * 32;
    const int srow = tid >> 2;
    const int spart = (tid & 3) ^ ((srow >> 1) & 3);

    // wxn tile (64 rows of this block's n0 slice), needed only at kt==8
    gl16(&wxn[(size_t)(n0 + srow) * 32 + spart * 8], &Xl[(wid * 64) * 8]);

    v4f accr[4][2] = {}, accz[4][2] = {}, acch[4][2] = {}, accn[4][2] = {};

    for (int kt = 0; kt < 9; ++kt) {
#pragma unroll
        for (int p = 0; p < 2; ++p) {
            const u16* ga = (kt < 8)
                ? &Am[(size_t)(m0 + p * 64 + srow) * 256 + kt * 32 + spart * 8]
                : &xpad[(size_t)(m0 + p * 64 + srow) * 32 + spart * 8];
            gl16(ga, &Al[(p * 256 + wid * 64) * 8]);
        }
#pragma unroll
        for (int p = 0; p < 3; ++p)
            gl16(&wfull[(size_t)(p * 256 + n0 + srow) * 288 + kt * 32 + spart * 8],
                 &Bl[(p * 256 + wid * 64) * 8]);
        __syncthreads();

        v8s af[4];
#pragma unroll
        for (int i = 0; i < 4; ++i)
            af[i] = *(const v8s*)&Al[(wm + i * 16 + ln) * 32 + qs8];
        v8s bfr[3][2];
#pragma unroll
        for (int g = 0; g < 3; ++g)
#pragma unroll
            for (int j = 0; j < 2; ++j)
                bfr[g][j] = *(const v8s*)&Bl[(g * 64 + wn + j * 16 + ln) * 32 + qs8];
#pragma unroll
        for (int i = 0; i < 4; ++i)
#pragma unroll
            for (int j = 0; j < 2; ++j) {
                accr[i][j] = __builtin_amdgcn_mfma_f32_16x16x32_bf16(af[i], bfr[0][j], accr[i][j], 0, 0, 0);
                accz[i][j] = __builtin_amdgcn_mfma_f32_16x16x32_bf16(af[i], bfr[1][j], accz[i][j], 0, 0, 0);
                acch[i][j] = __builtin_amdgcn_mfma_f32_16x16x32_bf16(af[i], bfr[2][j], acch[i][j], 0, 0, 0);
            }
        if (kt == 8) {
            v8s bfn[2];
#pragma unroll
            for (int j = 0; j < 2; ++j)
                bfn[j] = *(const v8s*)&Xl[(wn + j * 16 + ln) * 32 + qs8];
#pragma unroll
            for (int i = 0; i < 4; ++i)
#pragma unroll
                for (int j = 0; j < 2; ++j)
                    accn[i][j] = __builtin_amdgcn_mfma_f32_16x16x32_bf16(af[i], bfn[j], accn[i][j], 0, 0, 0);
        }
        __syncthreads();
    }

#pragma unroll
    for (int i = 0; i < 4; ++i)
#pragma unroll
        for (int j = 0; j < 2; ++j) {
            int gc = n0 + wn + j * 16 + ln;
#pragma unroll
            for (int r = 0; r < 4; ++r) {
                int gr = m0 + wm + i * 16 + q * 4 + r;
                float rg = sigm(accr[i][j][r]);
                float zg = sigm(accz[i][j][r]);
                float nn = tanh_fast(accn[i][j][r] + rg * acch[i][j][r]);
                float hp = bf2f(hprev[(size_t)gr * 256 + gc]);
                hout[(size_t)gr * 256 + gc] = f2bf((1.f - zg) * nn + zg * hp);
            }
        }
}

// ---------------------------------------------------------------------------
// Step-0 xpad from the three input frames.
// ---------------------------------------------------------------------------
__global__ __launch_bounds__(256) void init_xpad(
    const float* __restrict__ x0, const float* __restrict__ xp,
    const float* __restrict__ xp2, u16* __restrict__ xpad)
{
    int m = blockIdx.x * 256 + threadIdx.x;
    float a0 = x0[m * 3 + 0], a1 = x0[m * 3 + 1], a2 = x0[m * 3 + 2];
    float b0 = xp[m * 3 + 0], b1 = xp[m * 3 + 1], b2 = xp[m * 3 + 2];
    float c0 = xp2[m * 3 + 0], c1 = xp2[m * 3 + 1], c2 = xp2[m * 3 + 2];
    unsigned t[32];
#pragma unroll
    for (int i = 0; i < 32; ++i) t[i] = 0;
    t[0] = f2bf(a0); t[1] = f2bf(a1); t[2] = f2bf(a2);
    t[3] = f2bf(b0 - c0); t[4] = f2bf(b1 - c1); t[5] = f2bf(b2 - c2);
    t[6] = f2bf(a0 - 2.f * b0 + c0);
    t[7] = f2bf(a1 - 2.f * b1 + c1);
    t[8] = f2bf(a2 - 2.f * b2 + c2);
    t[9] = f2bf(1.f);
    uint4* dst = (uint4*)&xpad[(size_t)m * 32];
#pragma unroll
    for (int wq = 0; wq < 4; ++wq) {
        uint4 u;
        u.x = t[wq * 8 + 0] | (t[wq * 8 + 1] << 16);
        u.y = t[wq * 8 + 2] | (t[wq * 8 + 3] << 16);
        u.z = t[wq * 8 + 4] | (t[wq * 8 + 5] << 16);
        u.w = t[wq * 8 + 6] | (t[wq * 8 + 7] << 16);
        dst[wq] = u;
    }
}

// ---------------------------------------------------------------------------
// hidden [N,C,V] fp32 -> h[(n,v),c] bf16.
// ---------------------------------------------------------------------------
__global__ __launch_bounds__(256) void transpose_h(
    const float* __restrict__ hidden, u16* __restrict__ hA)
{
    __shared__ float hl[256 * VN];
    const int n = blockIdx.x, tid = threadIdx.x;
    const uint4* src = (const uint4*)(hidden + (size_t)n * 256 * VN);
    for (int idx = tid; idx < 256 * VN / 4; idx += 256)
        ((uint4*)hl)[idx] = src[idx];
    __syncthreads();
    size_t base = (size_t)n * VN * 256;
    for (int idx = tid; idx < VN * 256; idx += 256) {
        int v = idx >> 8, c = idx & 255;
        hA[base + idx] = f2bf(hl[c * VN + v]);
    }
}

// ---------------------------------------------------------------------------
// Weight packing (once per call).
// wfull[768,288]: row g*256+c -> cols 0..255 = Wh_g[c,:],
//   256..264 = x-weights (g<2), 265 = bias (g<2), rest 0.
// wxn[256,32]:   row c -> 0..8 = Win[c,:], 9 = b_in[c], rest 0.
// ---------------------------------------------------------------------------
__global__ __launch_bounds__(256) void pack_weights(
    const float* __restrict__ Whr, const float* __restrict__ Whi,
    const float* __restrict__ Whh, const float* __restrict__ convw_f,
    const float* __restrict__ W1f, const float* __restrict__ W2f,
    const float* __restrict__ Af, const float* __restrict__ emul,
    const float* __restrict__ eadd, const float* __restrict__ Wir,
    const float* __restrict__ Wii, const float* __restrict__ Win,
    const float* __restrict__ bir, const float* __restrict__ bii,
    const float* __restrict__ b_in, const float* __restrict__ convb_f,
    const float* __restrict__ b1f, const float* __restrict__ b2f,
    const float* __restrict__ W3f, const float* __restrict__ b3f,
    u16* __restrict__ wfull, u16* __restrict__ wxn, u16* __restrict__ convw,
    u16* __restrict__ w1, u16* __restrict__ w2, float* __restrict__ aadj,
    float* __restrict__ convb, float* __restrict__ b1, float* __restrict__ b2,
    float* __restrict__ w3, float* __restrict__ b3)
{
    int gid = blockIdx.x * 256 + threadIdx.x;
    int stride = gridDim.x * 256;
    for (int i = gid; i < 768 * 288; i += stride) {
        int row = i / 288, col = i - row * 288;
        int g = row >> 8, c = row & 255;
        float v = 0.f;
        if (col < 256)
            v = (g == 0 ? Whr : (g == 1 ? Whi : Whh))[c * 256 + col];
        else if (col < 265) {
            int tcol = col - 256;
            v = (g == 0 ? Wir[c * 9 + tcol] : (g == 1 ? Wii[c * 9 + tcol] : 0.f));
        } else if (col == 265)
            v = (g == 0 ? bir[c] : (g == 1 ? bii[c] : 0.f));
        wfull[i] = f2bf(v);
    }
    for (int i = gid; i < 256 * 32; i += stride) {
        int c = i >> 5, col = i & 31;
        float v = 0.f;
        if (col < 9) v = Win[c * 9 + col];
        else if (col == 9) v = b_in[c];
        wxn[i] = f2bf(v);
    }
    for (int i = gid; i < 65536; i += stride) {
        w1[i] = f2bf(W1f[i]);
        w2[i] = f2bf(W2f[i]);
    }
    for (int i = gid; i < 196608; i += stride) convw[i] = f2bf(convw_f[i]);
    for (int i = gid; i < KNUM * VN * VN; i += stride)
        aadj[i] = Af[i] * emul[i] + eadd[i];
    for (int i = gid; i < 256; i += stride) { b1[i] = b1f[i]; b2[i] = b2f[i]; }
    for (int i = gid; i < 768; i += stride) { convb[i] = convb_f[i]; w3[i] = W3f[i]; }
    if (gid < 3) b3[gid] = b3f[gid];
}

// ---------------------------------------------------------------------------
extern "C" void kernel_launch(void* const* d_in, const int* in_sizes, int n_in,
                              void* d_out, int out_size, void* d_ws, size_t ws_size,
                              hipStream_t stream)
{
    const float* inputs   = (const float*)d_in[0];
    const float* inputs_p = (const float*)d_in[1];
    const float* inputs_p2= (const float*)d_in[2];
    const float* hidden   = (const float*)d_in[3];
    const float* Af       = (const float*)d_in[4];
    const float* emul     = (const float*)d_in[5];
    const float* eadd     = (const float*)d_in[6];
    const float* conv_w   = (const float*)d_in[7];
    const float* conv_b   = (const float*)d_in[8];
    const float* Wir      = (const float*)d_in[9];
    const float* bir      = (const float*)d_in[10];
    const float* Wii      = (const float*)d_in[11];
    const float* bii      = (const float*)d_in[12];
    const float* Win      = (const float*)d_in[13];
    const float* b_in     = (const float*)d_in[14];
    const float* Whr      = (const float*)d_in[15];
    const float* Whi      = (const float*)d_in[16];
    const float* Whh      = (const float*)d_in[17];
    const float* W1f      = (const float*)d_in[18];
    const float* b1f      = (const float*)d_in[19];
    const float* W2f      = (const float*)d_in[20];
    const float* b2f      = (const float*)d_in[21];
    const float* W3f      = (const float*)d_in[22];
    const float* b3f      = (const float*)d_in[23];
    float* out = (float*)d_out;

    const size_t M = M_ROWS;
    char* ws = (char*)d_ws;
    size_t off = 0;
    auto alloc = [&](size_t bytes) -> void* {
        void* p = ws + off;
        off = (off + bytes + 255) & ~(size_t)255;
        return p;
    };
    u16* hA    = (u16*)alloc(M * 256 * 2);
    u16* hB    = (u16*)alloc(M * 256 * 2);
    u16* msg   = (u16*)alloc(M * 256 * 2);
    u16* ybuf  = (u16*)alloc(M * 768 * 2);
    u16* xpad  = (u16*)alloc(M * 32 * 2);
    float* pa  = (float*)alloc(M * 3 * 4);
    float* pb  = (float*)alloc(M * 3 * 4);
    float* pc  = (float*)alloc(M * 3 * 4);
    float* rs0 = (float*)alloc(M * 3 * 4);
    float* rs1 = (float*)alloc(M * 3 * 4);
    u16* wfull = (u16*)alloc(768 * 288 * 2);
    u16* wxn   = (u16*)alloc(256 * 32 * 2);
    u16* convw = (u16*)alloc(196608 * 2);
    u16* w1    = (u16*)alloc(65536 * 2);
    u16* w2    = (u16*)alloc(65536 * 2);
    float* aadj  = (float*)alloc(KNUM * VN * VN * 4);
    float* convb = (float*)alloc(768 * 4);
    float* b1    = (float*)alloc(256 * 4);
    float* b2    = (float*)alloc(256 * 4);
    float* w3    = (float*)alloc(768 * 4);
    float* b3    = (float*)alloc(16);
    if (off > ws_size) return;

    pack_weights<<<512, 256, 0, stream>>>(
        Whr, Whi, Whh, conv_w, W1f, W2f, Af, emul, eadd, Wir, Wii, Win,
        bir, bii, b_in, conv_b, b1f, b2f, W3f, b3f,
        wfull, wxn, convw, w1, w2, aadj, convb, b1, b2, w3, b3);
    transpose_h<<<NBATCH, 256, 0, stream>>>(hidden, hA);
    init_xpad<<<M_ROWS / 256, 256, 0, stream>>>(inputs, inputs_p, inputs_p2, xpad);
    hipMemcpyAsync(pa, inputs,    M * 3 * 4, hipMemcpyDeviceToDevice, stream);
    hipMemcpyAsync(pb, inputs_p,  M * 3 * 4, hipMemcpyDeviceToDevice, stream);
    hipMemcpyAsync(pc, inputs_p2, M * 3 * 4, hipMemcpyDeviceToDevice, stream);

    u16* hcur = hA;  u16* hnext = hB;
    float* P1 = pa;  float* P2 = pb;  float* P3 = pc;
    u16* hd  = ybuf;
    const int MB = M_ROWS / 128;  // 832

    for (int s = 0; s < TS; ++s) {
        const u16* m_ptr;
        if (s < 10) {
            gemm_nt<0><<<dim3(MB, 6), 256, 0, stream>>>(hcur, convw, convb, ybuf, 768);
            graph_mix<<<NBATCH, 256, 0, stream>>>(ybuf, aadj, msg);
            m_ptr = msg;
        } else {
            m_ptr = hcur;
        }
        gru_fused<<<dim3(MB, 4), 256, 0, stream>>>(m_ptr, xpad, hcur, hnext,
                                                   wfull, wxn);
        gemm_nt<1><<<dim3(MB, 2), 256, 0, stream>>>(hnext, w1, b1, hd, 256);
        // W2 gemm fused with W3 head projection: hd2 never touches HBM
        gemm_head<<<dim3(MB, 2), 256, 0, stream>>>(hd, w2, b2, w3, rs0, rs1);
        head_fin<<<M_ROWS / 256, 256, 0, stream>>>(rs0, rs1, b3, P1, P2, P3,
                                                   xpad, out, s);
        float* t = P3; P3 = P2; P2 = P1; P1 = t;
        u16* ht = hcur; hcur = hnext; hnext = ht;
    }
}

// Round 5
// 6020.253 us; speedup vs baseline: 1.3843x; 1.0651x over previous
//
#include <hip/hip_runtime.h>

// Problem constants (fixed by the reference)
#define M_ROWS 106496   // 4096*26  (n,v) rows
#define NBATCH 4096
#define VN 26
#define KNUM 3
#define TS 25

typedef unsigned short u16;
typedef __attribute__((ext_vector_type(8))) short v8s;
typedef __attribute__((ext_vector_type(4))) float v4f;

__device__ __forceinline__ u16 f2bf(float f) {
    unsigned u = __float_as_uint(f);
    u += 0x7FFF + ((u >> 16) & 1);   // RNE
    return (u16)(u >> 16);
}
__device__ __forceinline__ float bf2f(u16 h) {
    return __uint_as_float(((unsigned)h) << 16);
}
__device__ __forceinline__ float sigm(float x) {
    return 1.f / (1.f + __expf(-x));
}
__device__ __forceinline__ float tanh_fast(float x) {
    return 2.f / (1.f + __expf(-2.f * x)) - 1.f;
}

// Async global->LDS, 16B per lane. LDS dest must be the wave-uniform base;
// HW adds lane*16. Staging layout stays LINEAR in lane order; the LDS
// swizzle is realized by pre-permuting the per-lane GLOBAL source chunk
// (rule: both-sides-or-neither with global_load_lds).
typedef const __attribute__((address_space(1))) unsigned int* gas_t;
typedef __attribute__((address_space(3))) unsigned int* las_t;
__device__ __forceinline__ void gl16(const void* g, void* l) {
    __builtin_amdgcn_global_load_lds((gas_t)g, (las_t)l, 16, 0, 0);
}

// ---------------------------------------------------------------------------
// Generic NT gemm: C[M,nc] = A[M,256](bf16) @ Bt[nc,256](bf16)^T + bias
// BM=128, BN=128, BK=32; 256 threads = 4 waves (2x2), each wave 64x64.
// 2-phase double-buffered pipeline + chunk-XOR swizzle (MEASURED good, R1/R3).
// Now used only for the s<10 conv gemm (nc=768). DO NOT TOUCH without A/B.
// ---------------------------------------------------------------------------
template <int ACT>
__global__ __launch_bounds__(256) void gemm_nt(
    const u16* __restrict__ A, const u16* __restrict__ Bt,
    const float* __restrict__ bias, u16* __restrict__ C, int nc)
{
    __shared__ u16 Al[2][128 * 32];
    __shared__ u16 Bl[2][128 * 32];
    const int m0 = blockIdx.x * 128;
    const int n0 = blockIdx.y * 128;
    const int tid = threadIdx.x;
    const int wid = tid >> 6, lane = tid & 63;
    const int ln = lane & 15, q = lane >> 4;
    const int qs8 = (q ^ ((ln >> 1) & 3)) * 8;          // swizzled read chunk
    const int wm = (wid >> 1) * 64, wn = (wid & 1) * 64;
    const int srow = tid >> 2;
    const int spart = (tid & 3) ^ ((srow >> 1) & 3);    // swizzled src chunk

    const u16* gA0 = &A[(size_t)(m0 + srow) * 256 + spart * 8];
    const u16* gB0 = &Bt[(size_t)(n0 + srow) * 256 + spart * 8];

#define STG(b, kk) do {                                                     \
        gl16(gA0 + (kk) * 32,            &Al[b][wid * 512]);                \
        gl16(gA0 + 64 * 256 + (kk) * 32, &Al[b][2048 + wid * 512]);         \
        gl16(gB0 + (kk) * 32,            &Bl[b][wid * 512]);                \
        gl16(gB0 + 64 * 256 + (kk) * 32, &Bl[b][2048 + wid * 512]);         \
    } while (0)

    v4f acc[4][4] = {};
    STG(0, 0);
    __syncthreads();
#pragma unroll
    for (int kt = 0; kt < 8; ++kt) {
        const int cb = kt & 1, nb = cb ^ 1;
        if (kt < 7) STG(nb, kt + 1);
        v8s af[4], bfv[4];
#pragma unroll
        for (int i = 0; i < 4; ++i)
            af[i] = *(const v8s*)&Al[cb][(wm + i * 16 + ln) * 32 + qs8];
#pragma unroll
        for (int j = 0; j < 4; ++j)
            bfv[j] = *(const v8s*)&Bl[cb][(wn + j * 16 + ln) * 32 + qs8];
#pragma unroll
        for (int i = 0; i < 4; ++i)
#pragma unroll
            for (int j = 0; j < 4; ++j)
                acc[i][j] = __builtin_amdgcn_mfma_f32_16x16x32_bf16(
                    af[i], bfv[j], acc[i][j], 0, 0, 0);
        __syncthreads();
    }
#undef STG
#pragma unroll
    for (int i = 0; i < 4; ++i)
#pragma unroll
        for (int j = 0; j < 4; ++j) {
            int gc = n0 + wn + j * 16 + ln;
            float b = bias[gc];
#pragma unroll
            for (int r = 0; r < 4; ++r) {
                int gr = m0 + wm + i * 16 + q * 4 + r;
                float v = acc[i][j][r] + b;
                if (ACT) v = v > 0.f ? v : 0.1f * v;
                C[(size_t)gr * nc + gc] = f2bf(v);
            }
        }
}

// ---------------------------------------------------------------------------
// Fused MLP head: one kernel for W1 -> W2 -> W3 -> finisher.
// BM=64 rows/block, grid 1664. Phase 1: hd = leaky(A@W1^T+b1) into swizzled
// LDS (never HBM). Phase 2: hd2 = leaky(hd@W2^T+b2) in regs, W3 dot via
// 16-lane butterfly + LDS cross-wave combine, then in-block finisher emits
// out/pnew/xpad. Removes the 109 MB/step hd round-trip + 2 launches.
// hd LDS swizzle: chunk' = chunk ^ (row&15); row stride 512B is bank-neutral
// so XOR gives 2 lanes/bank-group at distinct addrs (free, m136).
// LDS: 8(Ast)+32(Bst)+32(hdl)+1.5 = 75 KB -> 2 blocks/CU.
// ---------------------------------------------------------------------------
__global__ __launch_bounds__(256) void mlp_head(
    const u16* __restrict__ A, const u16* __restrict__ w1,
    const float* __restrict__ b1, const u16* __restrict__ w2,
    const float* __restrict__ b2, const float* __restrict__ w3,
    const float* __restrict__ b3, const float* __restrict__ p1,
    const float* __restrict__ p2, float* __restrict__ pnew,
    u16* __restrict__ xpad, float* __restrict__ out, int s)
{
    __shared__ u16 Ast[2][64 * 32];     // 2 x 4 KB
    __shared__ u16 Bst[2][256 * 32];    // 2 x 16 KB
    __shared__ u16 hdl[64 * 256];       // 32 KB, chunk-XOR swizzled
    __shared__ float resl[2][64][3];    // 1.5 KB
    const int m0 = blockIdx.x * 64;
    const int tid = threadIdx.x;
    const int wid = tid >> 6, lane = tid & 63;
    const int ln = lane & 15, q = lane >> 4;
    const int qs8 = (q ^ ((ln >> 1) & 3)) * 8;
    const int wm = (wid >> 1) * 32;     // 0 / 32
    const int wn = (wid & 1) * 128;     // 0 / 128
    const int wnh = wid & 1;
    const int srow = tid >> 2;
    const int spart = (tid & 3) ^ ((srow >> 1) & 3);

    const u16* gA0 = &A[(size_t)(m0 + srow) * 256 + spart * 8];
    const u16* gW1 = &w1[(size_t)srow * 256 + spart * 8];
    const u16* gW2 = &w2[(size_t)srow * 256 + spart * 8];

#define STGA(b, kk) gl16(gA0 + (kk) * 32, &Ast[b][wid * 512])
#define STGB(b, kk, W) do {                                                 \
        gl16(W + (kk) * 32,             &Bst[b][wid * 512]);                \
        gl16(W + 64 * 256 + (kk) * 32,  &Bst[b][2048 + wid * 512]);         \
        gl16(W + 128 * 256 + (kk) * 32, &Bst[b][4096 + wid * 512]);         \
        gl16(W + 192 * 256 + (kk) * 32, &Bst[b][6144 + wid * 512]);         \
    } while (0)

    // ---- phase 1: acc = A @ W1^T ----
    v4f acc[2][8] = {};
    STGA(0, 0); STGB(0, 0, gW1);
    __syncthreads();
    for (int kt = 0; kt < 8; ++kt) {
        const int cb = kt & 1, nb = cb ^ 1;
        if (kt < 7) { STGA(nb, kt + 1); STGB(nb, kt + 1, gW1); }
        else        { STGB(nb, 0, gW2); }
        v8s af[2], bf[8];
#pragma unroll
        for (int i = 0; i < 2; ++i)
            af[i] = *(const v8s*)&Ast[cb][(wm + i * 16 + ln) * 32 + qs8];
#pragma unroll
        for (int j = 0; j < 8; ++j)
            bf[j] = *(const v8s*)&Bst[cb][(wn + j * 16 + ln) * 32 + qs8];
#pragma unroll
        for (int i = 0; i < 2; ++i)
#pragma unroll
            for (int j = 0; j < 8; ++j)
                acc[i][j] = __builtin_amdgcn_mfma_f32_16x16x32_bf16(
                    af[i], bf[j], acc[i][j], 0, 0, 0);
        __syncthreads();
    }

    // ---- epilogue 1: hd -> swizzled LDS ----
#pragma unroll
    for (int i = 0; i < 2; ++i)
#pragma unroll
        for (int j = 0; j < 8; ++j) {
            int col = wn + j * 16 + ln;
            float bb = b1[col];
#pragma unroll
            for (int r = 0; r < 4; ++r) {
                int row = wm + i * 16 + q * 4 + r;
                float v = acc[i][j][r] + bb;
                v = v > 0.f ? v : 0.1f * v;
                int ch = (col >> 3) ^ (row & 15);
                hdl[row * 256 + ch * 8 + (col & 7)] = f2bf(v);
            }
        }
    __syncthreads();

    // ---- phase 2: acc2 = hd @ W2^T ----
    v4f acc2[2][8] = {};
    for (int kt = 0; kt < 8; ++kt) {
        const int cb = kt & 1, nb = cb ^ 1;
        if (kt < 7) STGB(nb, kt + 1, gW2);
        v8s af[2], bf[8];
#pragma unroll
        for (int i = 0; i < 2; ++i) {
            int row = wm + i * 16 + ln;
            int ch = (kt * 4 + q) ^ (row & 15);
            af[i] = *(const v8s*)&hdl[row * 256 + ch * 8];
        }
#pragma unroll
        for (int j = 0; j < 8; ++j)
            bf[j] = *(const v8s*)&Bst[cb][(wn + j * 16 + ln) * 32 + qs8];
#pragma unroll
        for (int i = 0; i < 2; ++i)
#pragma unroll
            for (int j = 0; j < 8; ++j)
                acc2[i][j] = __builtin_amdgcn_mfma_f32_16x16x32_bf16(
                    af[i], bf[j], acc2[i][j], 0, 0, 0);
        __syncthreads();
    }
#undef STGA
#undef STGB

    // ---- epilogue 2: leaky + W3 partial dot + butterfly over ln ----
    float part[3][2][4] = {};
#pragma unroll
    for (int j = 0; j < 8; ++j) {
        int col = wn + j * 16 + ln;
        float bb = b2[col];
        float w30 = w3[col], w31 = w3[256 + col], w32 = w3[512 + col];
#pragma unroll
        for (int i = 0; i < 2; ++i)
#pragma unroll
            for (int r = 0; r < 4; ++r) {
                float v = acc2[i][j][r] + bb;
                v = v > 0.f ? v : 0.1f * v;
                part[0][i][r] += v * w30;
                part[1][i][r] += v * w31;
                part[2][i][r] += v * w32;
            }
    }
#pragma unroll
    for (int off = 1; off < 16; off <<= 1)
#pragma unroll
        for (int t = 0; t < 3; ++t)
#pragma unroll
            for (int i = 0; i < 2; ++i)
#pragma unroll
                for (int r = 0; r < 4; ++r)
                    part[t][i][r] += __shfl_xor(part[t][i][r], off, 16);
    if (ln == 0) {
#pragma unroll
        for (int i = 0; i < 2; ++i)
#pragma unroll
            for (int r = 0; r < 4; ++r) {
                int row = wm + i * 16 + q * 4 + r;
#pragma unroll
                for (int t = 0; t < 3; ++t)
                    resl[wnh][row][t] = part[t][i][r];
            }
    }
    __syncthreads();

    // ---- in-block finisher (64 threads, one row each) ----
    if (tid < 64) {
        int m = m0 + tid;
        float s0 = resl[0][tid][0] + resl[1][tid][0];
        float s1 = resl[0][tid][1] + resl[1][tid][1];
        float s2 = resl[0][tid][2] + resl[1][tid][2];
        float a0 = p1[m * 3 + 0], a1 = p1[m * 3 + 1], a2 = p1[m * 3 + 2];
        float c0 = p2[m * 3 + 0], c1 = p2[m * 3 + 1], c2 = p2[m * 3 + 2];
        float o0 = a0 + s0 + b3[0];
        float o1 = a1 + s1 + b3[1];
        float o2 = a2 + s2 + b3[2];
        size_t ob = ((size_t)m * TS + s) * 3;
        out[ob + 0] = o0; out[ob + 1] = o1; out[ob + 2] = o2;
        pnew[m * 3 + 0] = o0; pnew[m * 3 + 1] = o1; pnew[m * 3 + 2] = o2;
        unsigned t[32];
#pragma unroll
        for (int i = 0; i < 32; ++i) t[i] = 0;
        t[0] = f2bf(o0); t[1] = f2bf(o1); t[2] = f2bf(o2);
        t[3] = f2bf(a0 - c0); t[4] = f2bf(a1 - c1); t[5] = f2bf(a2 - c2);
        t[6] = f2bf(o0 - 2.f * a0 + c0);
        t[7] = f2bf(o1 - 2.f * a1 + c1);
        t[8] = f2bf(o2 - 2.f * a2 + c2);
        t[9] = f2bf(1.f);
        uint4* dst = (uint4*)&xpad[(size_t)m * 32];
#pragma unroll
        for (int wq = 0; wq < 4; ++wq) {
            uint4 u;
            u.x = t[wq * 8 + 0] | (t[wq * 8 + 1] << 16);
            u.y = t[wq * 8 + 2] | (t[wq * 8 + 3] << 16);
            u.z = t[wq * 8 + 4] | (t[wq * 8 + 5] << 16);
            u.w = t[wq * 8 + 6] | (t[wq * 8 + 7] << 16);
            dst[wq] = u;
        }
    }
}

// ---------------------------------------------------------------------------
// Graph mix: msg[(n,w),c] = sum_{k,v} y[(n,v),k*256+c] * aadj[k][v][w]
// ---------------------------------------------------------------------------
__global__ __launch_bounds__(256) void graph_mix(
    const u16* __restrict__ y, const float* __restrict__ aadj,
    u16* __restrict__ msg)
{
    __shared__ u16 yl[VN * 768];
    const int n = blockIdx.x, tid = threadIdx.x;
    const uint4* src = (const uint4*)(y + (size_t)n * VN * 768);
    for (int idx = tid; idx < VN * 768 / 8; idx += 256)
        ((uint4*)yl)[idx] = src[idx];
    __syncthreads();
    const int c = tid;
    float acc[VN] = {};
    for (int k = 0; k < KNUM; ++k)
        for (int v = 0; v < VN; ++v) {
            float yv = bf2f(yl[v * 768 + k * 256 + c]);
            const float* ap = &aadj[(k * VN + v) * VN];
#pragma unroll
            for (int w = 0; w < VN; ++w) acc[w] += yv * ap[w];
        }
    size_t base = (size_t)n * VN * 256;
    for (int w = 0; w < VN; ++w) msg[base + w * 256 + c] = f2bf(acc[w]);
}

// ---------------------------------------------------------------------------
// Fused GRU, K=288: cols 0..255 = msg (Wh*), 256..287 = xpad (x-proj + bias).
// BYTE-EXACT R3 structure (115.5 us @ 20.4% occupancy, VGPR 116): rolled kt
// loop (NO unroll — R2's unroll cost 140 VGPR / 11% occ / 196 us), single
// LDS buffer, two barriers per K-step, constant-folded XOR swizzle.
// grid = (832, 4). DO NOT TOUCH.
// ---------------------------------------------------------------------------
__global__ __launch_bounds__(256) void gru_fused(
    const u16* __restrict__ Am, const u16* __restrict__ xpad,
    const u16* __restrict__ hprev, u16* __restrict__ hout,
    const u16* __restrict__ wfull, const u16* __restrict__ wxn)
{
    __shared__ u16 Al[128 * 32];   // 8 KB
    __shared__ u16 Bl[192 * 32];   // 12 KB
    __shared__ u16 Xl[64 * 32];    // 4 KB
    const int m0 = blockIdx.x * 128;
    const int n0 = blockIdx.y * 64;
    const int tid = threadIdx.x;
    const int wid = tid >> 6, lane = tid & 63;
    const int ln = lane & 15, q = lane >> 4;
    const int qs8 = (q ^ ((ln >> 1) & 3)) * 8;
    const int wm = (wid >> 1) * 64, wn = (wid & 1) * 32;
    const int srow = tid >> 2;
    const int spart = (tid & 3) ^ ((srow >> 1) & 3);

    // wxn tile (64 rows of this block's n0 slice), needed only at kt==8
    gl16(&wxn[(size_t)(n0 + srow) * 32 + spart * 8], &Xl[(wid * 64) * 8]);

    v4f accr[4][2] = {}, accz[4][2] = {}, acch[4][2] = {}, accn[4][2] = {};

    for (int kt = 0; kt < 9; ++kt) {
#pragma unroll
        for (int p = 0; p < 2; ++p) {
            const u16* ga = (kt < 8)
                ? &Am[(size_t)(m0 + p * 64 + srow) * 256 + kt * 32 + spart * 8]
                : &xpad[(size_t)(m0 + p * 64 + srow) * 32 + spart * 8];
            gl16(ga, &Al[(p * 256 + wid * 64) * 8]);
        }
#pragma unroll
        for (int p = 0; p < 3; ++p)
            gl16(&wfull[(size_t)(p * 256 + n0 + srow) * 288 + kt * 32 + spart * 8],
                 &Bl[(p * 256 + wid * 64) * 8]);
        __syncthreads();

        v8s af[4];
#pragma unroll
        for (int i = 0; i < 4; ++i)
            af[i] = *(const v8s*)&Al[(wm + i * 16 + ln) * 32 + qs8];
        v8s bfr[3][2];
#pragma unroll
        for (int g = 0; g < 3; ++g)
#pragma unroll
            for (int j = 0; j < 2; ++j)
                bfr[g][j] = *(const v8s*)&Bl[(g * 64 + wn + j * 16 + ln) * 32 + qs8];
#pragma unroll
        for (int i = 0; i < 4; ++i)
#pragma unroll
            for (int j = 0; j < 2; ++j) {
                accr[i][j] = __builtin_amdgcn_mfma_f32_16x16x32_bf16(af[i], bfr[0][j], accr[i][j], 0, 0, 0);
                accz[i][j] = __builtin_amdgcn_mfma_f32_16x16x32_bf16(af[i], bfr[1][j], accz[i][j], 0, 0, 0);
                acch[i][j] = __builtin_amdgcn_mfma_f32_16x16x32_bf16(af[i], bfr[2][j], acch[i][j], 0, 0, 0);
            }
        if (kt == 8) {
            v8s bfn[2];
#pragma unroll
            for (int j = 0; j < 2; ++j)
                bfn[j] = *(const v8s*)&Xl[(wn + j * 16 + ln) * 32 + qs8];
#pragma unroll
            for (int i = 0; i < 4; ++i)
#pragma unroll
                for (int j = 0; j < 2; ++j)
                    accn[i][j] = __builtin_amdgcn_mfma_f32_16x16x32_bf16(af[i], bfn[j], accn[i][j], 0, 0, 0);
        }
        __syncthreads();
    }

#pragma unroll
    for (int i = 0; i < 4; ++i)
#pragma unroll
        for (int j = 0; j < 2; ++j) {
            int gc = n0 + wn + j * 16 + ln;
#pragma unroll
            for (int r = 0; r < 4; ++r) {
                int gr = m0 + wm + i * 16 + q * 4 + r;
                float rg = sigm(accr[i][j][r]);
                float zg = sigm(accz[i][j][r]);
                float nn = tanh_fast(accn[i][j][r] + rg * acch[i][j][r]);
                float hp = bf2f(hprev[(size_t)gr * 256 + gc]);
                hout[(size_t)gr * 256 + gc] = f2bf((1.f - zg) * nn + zg * hp);
            }
        }
}

// ---------------------------------------------------------------------------
// Step-0 xpad from the three input frames.
// ---------------------------------------------------------------------------
__global__ __launch_bounds__(256) void init_xpad(
    const float* __restrict__ x0, const float* __restrict__ xp,
    const float* __restrict__ xp2, u16* __restrict__ xpad)
{
    int m = blockIdx.x * 256 + threadIdx.x;
    float a0 = x0[m * 3 + 0], a1 = x0[m * 3 + 1], a2 = x0[m * 3 + 2];
    float b0 = xp[m * 3 + 0], b1 = xp[m * 3 + 1], b2 = xp[m * 3 + 2];
    float c0 = xp2[m * 3 + 0], c1 = xp2[m * 3 + 1], c2 = xp2[m * 3 + 2];
    unsigned t[32];
#pragma unroll
    for (int i = 0; i < 32; ++i) t[i] = 0;
    t[0] = f2bf(a0); t[1] = f2bf(a1); t[2] = f2bf(a2);
    t[3] = f2bf(b0 - c0); t[4] = f2bf(b1 - c1); t[5] = f2bf(b2 - c2);
    t[6] = f2bf(a0 - 2.f * b0 + c0);
    t[7] = f2bf(a1 - 2.f * b1 + c1);
    t[8] = f2bf(a2 - 2.f * b2 + c2);
    t[9] = f2bf(1.f);
    uint4* dst = (uint4*)&xpad[(size_t)m * 32];
#pragma unroll
    for (int wq = 0; wq < 4; ++wq) {
        uint4 u;
        u.x = t[wq * 8 + 0] | (t[wq * 8 + 1] << 16);
        u.y = t[wq * 8 + 2] | (t[wq * 8 + 3] << 16);
        u.z = t[wq * 8 + 4] | (t[wq * 8 + 5] << 16);
        u.w = t[wq * 8 + 6] | (t[wq * 8 + 7] << 16);
        dst[wq] = u;
    }
}

// ---------------------------------------------------------------------------
// hidden [N,C,V] fp32 -> h[(n,v),c] bf16.
// ---------------------------------------------------------------------------
__global__ __launch_bounds__(256) void transpose_h(
    const float* __restrict__ hidden, u16* __restrict__ hA)
{
    __shared__ float hl[256 * VN];
    const int n = blockIdx.x, tid = threadIdx.x;
    const uint4* src = (const uint4*)(hidden + (size_t)n * 256 * VN);
    for (int idx = tid; idx < 256 * VN / 4; idx += 256)
        ((uint4*)hl)[idx] = src[idx];
    __syncthreads();
    size_t base = (size_t)n * VN * 256;
    for (int idx = tid; idx < VN * 256; idx += 256) {
        int v = idx >> 8, c = idx & 255;
        hA[base + idx] = f2bf(hl[c * VN + v]);
    }
}

// ---------------------------------------------------------------------------
// Weight packing (once per call).
// wfull[768,288]: row g*256+c -> cols 0..255 = Wh_g[c,:],
//   256..264 = x-weights (g<2), 265 = bias (g<2), rest 0.
// wxn[256,32]:   row c -> 0..8 = Win[c,:], 9 = b_in[c], rest 0.
// ---------------------------------------------------------------------------
__global__ __launch_bounds__(256) void pack_weights(
    const float* __restrict__ Whr, const float* __restrict__ Whi,
    const float* __restrict__ Whh, const float* __restrict__ convw_f,
    const float* __restrict__ W1f, const float* __restrict__ W2f,
    const float* __restrict__ Af, const float* __restrict__ emul,
    const float* __restrict__ eadd, const float* __restrict__ Wir,
    const float* __restrict__ Wii, const float* __restrict__ Win,
    const float* __restrict__ bir, const float* __restrict__ bii,
    const float* __restrict__ b_in, const float* __restrict__ convb_f,
    const float* __restrict__ b1f, const float* __restrict__ b2f,
    const float* __restrict__ W3f, const float* __restrict__ b3f,
    u16* __restrict__ wfull, u16* __restrict__ wxn, u16* __restrict__ convw,
    u16* __restrict__ w1, u16* __restrict__ w2, float* __restrict__ aadj,
    float* __restrict__ convb, float* __restrict__ b1, float* __restrict__ b2,
    float* __restrict__ w3, float* __restrict__ b3)
{
    int gid = blockIdx.x * 256 + threadIdx.x;
    int stride = gridDim.x * 256;
    for (int i = gid; i < 768 * 288; i += stride) {
        int row = i / 288, col = i - row * 288;
        int g = row >> 8, c = row & 255;
        float v = 0.f;
        if (col < 256)
            v = (g == 0 ? Whr : (g == 1 ? Whi : Whh))[c * 256 + col];
        else if (col < 265) {
            int tcol = col - 256;
            v = (g == 0 ? Wir[c * 9 + tcol] : (g == 1 ? Wii[c * 9 + tcol] : 0.f));
        } else if (col == 265)
            v = (g == 0 ? bir[c] : (g == 1 ? bii[c] : 0.f));
        wfull[i] = f2bf(v);
    }
    for (int i = gid; i < 256 * 32; i += stride) {
        int c = i >> 5, col = i & 31;
        float v = 0.f;
        if (col < 9) v = Win[c * 9 + col];
        else if (col == 9) v = b_in[c];
        wxn[i] = f2bf(v);
    }
    for (int i = gid; i < 65536; i += stride) {
        w1[i] = f2bf(W1f[i]);
        w2[i] = f2bf(W2f[i]);
    }
    for (int i = gid; i < 196608; i += stride) convw[i] = f2bf(convw_f[i]);
    for (int i = gid; i < KNUM * VN * VN; i += stride)
        aadj[i] = Af[i] * emul[i] + eadd[i];
    for (int i = gid; i < 256; i += stride) { b1[i] = b1f[i]; b2[i] = b2f[i]; }
    for (int i = gid; i < 768; i += stride) { convb[i] = convb_f[i]; w3[i] = W3f[i]; }
    if (gid < 3) b3[gid] = b3f[gid];
}

// ---------------------------------------------------------------------------
extern "C" void kernel_launch(void* const* d_in, const int* in_sizes, int n_in,
                              void* d_out, int out_size, void* d_ws, size_t ws_size,
                              hipStream_t stream)
{
    const float* inputs   = (const float*)d_in[0];
    const float* inputs_p = (const float*)d_in[1];
    const float* inputs_p2= (const float*)d_in[2];
    const float* hidden   = (const float*)d_in[3];
    const float* Af       = (const float*)d_in[4];
    const float* emul     = (const float*)d_in[5];
    const float* eadd     = (const float*)d_in[6];
    const float* conv_w   = (const float*)d_in[7];
    const float* conv_b   = (const float*)d_in[8];
    const float* Wir      = (const float*)d_in[9];
    const float* bir      = (const float*)d_in[10];
    const float* Wii      = (const float*)d_in[11];
    const float* bii      = (const float*)d_in[12];
    const float* Win      = (const float*)d_in[13];
    const float* b_in     = (const float*)d_in[14];
    const float* Whr      = (const float*)d_in[15];
    const float* Whi      = (const float*)d_in[16];
    const float* Whh      = (const float*)d_in[17];
    const float* W1f      = (const float*)d_in[18];
    const float* b1f      = (const float*)d_in[19];
    const float* W2f      = (const float*)d_in[20];
    const float* b2f      = (const float*)d_in[21];
    const float* W3f      = (const float*)d_in[22];
    const float* b3f      = (const float*)d_in[23];
    float* out = (float*)d_out;

    const size_t M = M_ROWS;
    char* ws = (char*)d_ws;
    size_t off = 0;
    auto alloc = [&](size_t bytes) -> void* {
        void* p = ws + off;
        off = (off + bytes + 255) & ~(size_t)255;
        return p;
    };
    // R3-exact allocation order (gru's measured-good environment).
    u16* hA    = (u16*)alloc(M * 256 * 2);
    u16* hB    = (u16*)alloc(M * 256 * 2);
    u16* msg   = (u16*)alloc(M * 256 * 2);
    u16* ybuf  = (u16*)alloc(M * 768 * 2);
    u16* xpad  = (u16*)alloc(M * 32 * 2);
    float* pa  = (float*)alloc(M * 3 * 4);
    float* pb  = (float*)alloc(M * 3 * 4);
    float* pc  = (float*)alloc(M * 3 * 4);
    u16* wfull = (u16*)alloc(768 * 288 * 2);
    u16* wxn   = (u16*)alloc(256 * 32 * 2);
    u16* convw = (u16*)alloc(196608 * 2);
    u16* w1    = (u16*)alloc(65536 * 2);
    u16* w2    = (u16*)alloc(65536 * 2);
    float* aadj  = (float*)alloc(KNUM * VN * VN * 4);
    float* convb = (float*)alloc(768 * 4);
    float* b1    = (float*)alloc(256 * 4);
    float* b2    = (float*)alloc(256 * 4);
    float* w3    = (float*)alloc(768 * 4);
    float* b3    = (float*)alloc(16);
    if (off > ws_size) return;

    pack_weights<<<512, 256, 0, stream>>>(
        Whr, Whi, Whh, conv_w, W1f, W2f, Af, emul, eadd, Wir, Wii, Win,
        bir, bii, b_in, conv_b, b1f, b2f, W3f, b3f,
        wfull, wxn, convw, w1, w2, aadj, convb, b1, b2, w3, b3);
    transpose_h<<<NBATCH, 256, 0, stream>>>(hidden, hA);
    init_xpad<<<M_ROWS / 256, 256, 0, stream>>>(inputs, inputs_p, inputs_p2, xpad);
    hipMemcpyAsync(pa, inputs,    M * 3 * 4, hipMemcpyDeviceToDevice, stream);
    hipMemcpyAsync(pb, inputs_p,  M * 3 * 4, hipMemcpyDeviceToDevice, stream);
    hipMemcpyAsync(pc, inputs_p2, M * 3 * 4, hipMemcpyDeviceToDevice, stream);

    u16* hcur = hA;  u16* hnext = hB;
    float* P1 = pa;  float* P2 = pb;  float* P3 = pc;
    const int MB = M_ROWS / 128;  // 832

    for (int s = 0; s < TS; ++s) {
        const u16* m_ptr;
        if (s < 10) {
            gemm_nt<0><<<dim3(MB, 6), 256, 0, stream>>>(hcur, convw, convb, ybuf, 768);
            graph_mix<<<NBATCH, 256, 0, stream>>>(ybuf, aadj, msg);
            m_ptr = msg;
        } else {
            m_ptr = hcur;
        }
        gru_fused<<<dim3(MB, 4), 256, 0, stream>>>(m_ptr, xpad, hcur, hnext,
                                                   wfull, wxn);
        // W1+W2+W3+finisher fused: hd/hd2 never touch HBM
        mlp_head<<<M_ROWS / 64, 256, 0, stream>>>(hnext, w1, b1, w2, b2, w3, b3,
                                                  P1, P2, P3, xpad, out, s);
        float* t = P3; P3 = P2; P2 = P1; P1 = t;
        u16* ht = hcur; hcur = hnext; hnext = ht;
    }
}

// Round 6
// 5914.174 us; speedup vs baseline: 1.4091x; 1.0179x over previous
//
#include <hip/hip_runtime.h>

// Problem constants (fixed by the reference)
#define M_ROWS 106496   // 4096*26  (n,v) rows
#define NBATCH 4096
#define VN 26
#define KNUM 3
#define TS 25

typedef unsigned short u16;
typedef __attribute__((ext_vector_type(8))) short v8s;
typedef __attribute__((ext_vector_type(4))) float v4f;

__device__ __forceinline__ u16 f2bf(float f) {
    unsigned u = __float_as_uint(f);
    u += 0x7FFF + ((u >> 16) & 1);   // RNE
    return (u16)(u >> 16);
}
__device__ __forceinline__ float bf2f(u16 h) {
    return __uint_as_float(((unsigned)h) << 16);
}
__device__ __forceinline__ float sigm(float x) {
    return 1.f / (1.f + __expf(-x));
}
__device__ __forceinline__ float tanh_fast(float x) {
    return 2.f / (1.f + __expf(-2.f * x)) - 1.f;
}

// Async global->LDS, 16B per lane. LDS dest must be the wave-uniform base;
// HW adds lane*16. Staging layout stays LINEAR in lane order; the LDS
// swizzle is realized by pre-permuting the per-lane GLOBAL source chunk
// (rule: both-sides-or-neither with global_load_lds).
typedef const __attribute__((address_space(1))) unsigned int* gas_t;
typedef __attribute__((address_space(3))) unsigned int* las_t;
__device__ __forceinline__ void gl16(const void* g, void* l) {
    __builtin_amdgcn_global_load_lds((gas_t)g, (las_t)l, 16, 0, 0);
}

// ---------------------------------------------------------------------------
// Fused conv-gemm + graph mix, one block per batch n. Replaces the
// gemm_nt<0> (163.6 MB ybuf write) + graph_mix (163.6 MB ybuf read) pair —
// the y-panel (26x768) lives entirely in LDS.
// BITWISE-identical to the old pair: y = fp32 MFMA acc in the same kt order,
// f2bf at the same point, mix in fp32 with the same k-outer/v-inner order,
// msg f2bf identical.
// Phase 1 (x2 passes of N=384): y = H(26x256) @ convw^T, H in swizzled LDS,
// convw streamed from L2 via gl16 single-buffered (gru-style two barriers).
// Phase 2: graph_mix from Yl (LDS) -> msg.
// LDS: Hl 16K + Yl 39K + Bst 24K = 79 KB -> 2 blocks/CU.
// ---------------------------------------------------------------------------
__global__ __launch_bounds__(256) void conv_mix(
    const u16* __restrict__ h, const u16* __restrict__ convw,
    const float* __restrict__ convb, const float* __restrict__ aadj,
    u16* __restrict__ msg)
{
    __shared__ u16 Hl[32 * 256];    // 16 KB, chunk-swizzled, rows 26..31 zero
    __shared__ u16 Yl[26 * 768];    // 39 KB, chunk ^ (row&7) swizzled
    __shared__ u16 Bst[384 * 32];   // 24 KB; reused as fp32 aadj for the mix
    const int n = blockIdx.x, tid = threadIdx.x;
    const int wid = tid >> 6, lane = tid & 63;
    const int ln = lane & 15, q = lane >> 4;
    const int qs8 = (q ^ ((ln >> 1) & 3)) * 8;
    const int wn = wid * 96;                 // 96 of 384 cols per wave
    const int srow = tid >> 2;
    const int spart = (tid & 3) ^ ((srow >> 1) & 3);

    // stage H (26 rows) swizzled via plain ds-writes; zero-pad rows 26..31
    for (int idx = tid; idx < 26 * 32; idx += 256) {
        int row = idx >> 5, g = idx & 31;
        uint4 v = *(const uint4*)&h[((size_t)n * 26 + row) * 256 + g * 8];
        int gs = (g & ~3) | ((g & 3) ^ ((row >> 1) & 3));
        *(uint4*)&Hl[row * 256 + gs * 8] = v;
    }
    {
        uint4 z = {0, 0, 0, 0};
        for (int idx = tid; idx < 6 * 32; idx += 256) {
            int row = 26 + (idx >> 5), g = idx & 31;
            *(uint4*)&Hl[row * 256 + g * 8] = z;
        }
    }

    const u16* gW0 = &convw[(size_t)srow * 256 + spart * 8];
    for (int p = 0; p < 2; ++p) {
        v4f acc[2][6] = {};
        const u16* gW = gW0 + (size_t)p * 384 * 256;
        for (int kt = 0; kt < 8; ++kt) {
#pragma unroll
            for (int t = 0; t < 6; ++t)
                gl16(gW + (size_t)t * 64 * 256 + kt * 32,
                     &Bst[t * 2048 + wid * 512]);
            __syncthreads();
            v8s af[2], bf[6];
#pragma unroll
            for (int i = 0; i < 2; ++i)
                af[i] = *(const v8s*)&Hl[(i * 16 + ln) * 256 + kt * 32 + qs8];
#pragma unroll
            for (int j = 0; j < 6; ++j)
                bf[j] = *(const v8s*)&Bst[(wn + j * 16 + ln) * 32 + qs8];
#pragma unroll
            for (int i = 0; i < 2; ++i)
#pragma unroll
                for (int j = 0; j < 6; ++j)
                    acc[i][j] = __builtin_amdgcn_mfma_f32_16x16x32_bf16(
                        af[i], bf[j], acc[i][j], 0, 0, 0);
            __syncthreads();
        }
        // epilogue: y rows < 26 -> swizzled Yl (bf16, same rounding point
        // as the old ybuf store)
#pragma unroll
        for (int i = 0; i < 2; ++i)
#pragma unroll
            for (int j = 0; j < 6; ++j) {
                int o = p * 384 + wn + j * 16 + ln;
                float cb = convb[o];
#pragma unroll
                for (int r = 0; r < 4; ++r) {
                    int row = i * 16 + q * 4 + r;
                    if (row < 26) {
                        float v = acc[i][j][r] + cb;
                        int ch = (o >> 3) ^ (row & 7);
                        Yl[row * 768 + ch * 8 + (o & 7)] = f2bf(v);
                    }
                }
            }
    }
    __syncthreads();
    // overlay fp32 aadj onto Bst (last Bst read was before the kt7 barrier)
    float* aadjl = (float*)Bst;
    for (int idx = tid; idx < KNUM * VN * VN; idx += 256) aadjl[idx] = aadj[idx];
    __syncthreads();

    // graph mix: identical loop order / arithmetic to the old graph_mix
    const int c = tid;
    float accm[VN];
#pragma unroll
    for (int w = 0; w < VN; ++w) accm[w] = 0.f;
    for (int k = 0; k < KNUM; ++k)
        for (int v = 0; v < VN; ++v) {
            int o = k * 256 + c;
            float yv = bf2f(Yl[v * 768 + ((o >> 3) ^ (v & 7)) * 8 + (o & 7)]);
            const float* ap = &aadjl[(k * VN + v) * VN];
#pragma unroll
            for (int w = 0; w < VN; ++w) accm[w] += yv * ap[w];
        }
    size_t base = (size_t)n * VN * 256;
#pragma unroll
    for (int w = 0; w < VN; ++w) msg[base + w * 256 + c] = f2bf(accm[w]);
}

// ---------------------------------------------------------------------------
// Fused MLP head: one kernel for W1 -> W2 -> W3 -> finisher (R5-exact,
// measured good). BM=64 rows/block, grid 1664. hd/hd2 never touch HBM.
// ---------------------------------------------------------------------------
__global__ __launch_bounds__(256) void mlp_head(
    const u16* __restrict__ A, const u16* __restrict__ w1,
    const float* __restrict__ b1, const u16* __restrict__ w2,
    const float* __restrict__ b2, const float* __restrict__ w3,
    const float* __restrict__ b3, const float* __restrict__ p1,
    const float* __restrict__ p2, float* __restrict__ pnew,
    u16* __restrict__ xpad, float* __restrict__ out, int s)
{
    __shared__ u16 Ast[2][64 * 32];     // 2 x 4 KB
    __shared__ u16 Bst[2][256 * 32];    // 2 x 16 KB
    __shared__ u16 hdl[64 * 256];       // 32 KB, chunk-XOR swizzled
    __shared__ float resl[2][64][3];    // 1.5 KB
    const int m0 = blockIdx.x * 64;
    const int tid = threadIdx.x;
    const int wid = tid >> 6, lane = tid & 63;
    const int ln = lane & 15, q = lane >> 4;
    const int qs8 = (q ^ ((ln >> 1) & 3)) * 8;
    const int wm = (wid >> 1) * 32;     // 0 / 32
    const int wn = (wid & 1) * 128;     // 0 / 128
    const int wnh = wid & 1;
    const int srow = tid >> 2;
    const int spart = (tid & 3) ^ ((srow >> 1) & 3);

    const u16* gA0 = &A[(size_t)(m0 + srow) * 256 + spart * 8];
    const u16* gW1 = &w1[(size_t)srow * 256 + spart * 8];
    const u16* gW2 = &w2[(size_t)srow * 256 + spart * 8];

#define STGA(b, kk) gl16(gA0 + (kk) * 32, &Ast[b][wid * 512])
#define STGB(b, kk, W) do {                                                 \
        gl16(W + (kk) * 32,             &Bst[b][wid * 512]);                \
        gl16(W + 64 * 256 + (kk) * 32,  &Bst[b][2048 + wid * 512]);         \
        gl16(W + 128 * 256 + (kk) * 32, &Bst[b][4096 + wid * 512]);         \
        gl16(W + 192 * 256 + (kk) * 32, &Bst[b][6144 + wid * 512]);         \
    } while (0)

    // ---- phase 1: acc = A @ W1^T ----
    v4f acc[2][8] = {};
    STGA(0, 0); STGB(0, 0, gW1);
    __syncthreads();
    for (int kt = 0; kt < 8; ++kt) {
        const int cb = kt & 1, nb = cb ^ 1;
        if (kt < 7) { STGA(nb, kt + 1); STGB(nb, kt + 1, gW1); }
        else        { STGB(nb, 0, gW2); }
        v8s af[2], bf[8];
#pragma unroll
        for (int i = 0; i < 2; ++i)
            af[i] = *(const v8s*)&Ast[cb][(wm + i * 16 + ln) * 32 + qs8];
#pragma unroll
        for (int j = 0; j < 8; ++j)
            bf[j] = *(const v8s*)&Bst[cb][(wn + j * 16 + ln) * 32 + qs8];
#pragma unroll
        for (int i = 0; i < 2; ++i)
#pragma unroll
            for (int j = 0; j < 8; ++j)
                acc[i][j] = __builtin_amdgcn_mfma_f32_16x16x32_bf16(
                    af[i], bf[j], acc[i][j], 0, 0, 0);
        __syncthreads();
    }

    // ---- epilogue 1: hd -> swizzled LDS ----
#pragma unroll
    for (int i = 0; i < 2; ++i)
#pragma unroll
        for (int j = 0; j < 8; ++j) {
            int col = wn + j * 16 + ln;
            float bb = b1[col];
#pragma unroll
            for (int r = 0; r < 4; ++r) {
                int row = wm + i * 16 + q * 4 + r;
                float v = acc[i][j][r] + bb;
                v = v > 0.f ? v : 0.1f * v;
                int ch = (col >> 3) ^ (row & 15);
                hdl[row * 256 + ch * 8 + (col & 7)] = f2bf(v);
            }
        }
    __syncthreads();

    // ---- phase 2: acc2 = hd @ W2^T ----
    v4f acc2[2][8] = {};
    for (int kt = 0; kt < 8; ++kt) {
        const int cb = kt & 1, nb = cb ^ 1;
        if (kt < 7) STGB(nb, kt + 1, gW2);
        v8s af[2], bf[8];
#pragma unroll
        for (int i = 0; i < 2; ++i) {
            int row = wm + i * 16 + ln;
            int ch = (kt * 4 + q) ^ (row & 15);
            af[i] = *(const v8s*)&hdl[row * 256 + ch * 8];
        }
#pragma unroll
        for (int j = 0; j < 8; ++j)
            bf[j] = *(const v8s*)&Bst[cb][(wn + j * 16 + ln) * 32 + qs8];
#pragma unroll
        for (int i = 0; i < 2; ++i)
#pragma unroll
            for (int j = 0; j < 8; ++j)
                acc2[i][j] = __builtin_amdgcn_mfma_f32_16x16x32_bf16(
                    af[i], bf[j], acc2[i][j], 0, 0, 0);
        __syncthreads();
    }
#undef STGA
#undef STGB

    // ---- epilogue 2: leaky + W3 partial dot + butterfly over ln ----
    float part[3][2][4] = {};
#pragma unroll
    for (int j = 0; j < 8; ++j) {
        int col = wn + j * 16 + ln;
        float bb = b2[col];
        float w30 = w3[col], w31 = w3[256 + col], w32 = w3[512 + col];
#pragma unroll
        for (int i = 0; i < 2; ++i)
#pragma unroll
            for (int r = 0; r < 4; ++r) {
                float v = acc2[i][j][r] + bb;
                v = v > 0.f ? v : 0.1f * v;
                part[0][i][r] += v * w30;
                part[1][i][r] += v * w31;
                part[2][i][r] += v * w32;
            }
    }
#pragma unroll
    for (int off = 1; off < 16; off <<= 1)
#pragma unroll
        for (int t = 0; t < 3; ++t)
#pragma unroll
            for (int i = 0; i < 2; ++i)
#pragma unroll
                for (int r = 0; r < 4; ++r)
                    part[t][i][r] += __shfl_xor(part[t][i][r], off, 16);
    if (ln == 0) {
#pragma unroll
        for (int i = 0; i < 2; ++i)
#pragma unroll
            for (int r = 0; r < 4; ++r) {
                int row = wm + i * 16 + q * 4 + r;
#pragma unroll
                for (int t = 0; t < 3; ++t)
                    resl[wnh][row][t] = part[t][i][r];
            }
    }
    __syncthreads();

    // ---- in-block finisher (64 threads, one row each) ----
    if (tid < 64) {
        int m = m0 + tid;
        float s0 = resl[0][tid][0] + resl[1][tid][0];
        float s1 = resl[0][tid][1] + resl[1][tid][1];
        float s2 = resl[0][tid][2] + resl[1][tid][2];
        float a0 = p1[m * 3 + 0], a1 = p1[m * 3 + 1], a2 = p1[m * 3 + 2];
        float c0 = p2[m * 3 + 0], c1 = p2[m * 3 + 1], c2 = p2[m * 3 + 2];
        float o0 = a0 + s0 + b3[0];
        float o1 = a1 + s1 + b3[1];
        float o2 = a2 + s2 + b3[2];
        size_t ob = ((size_t)m * TS + s) * 3;
        out[ob + 0] = o0; out[ob + 1] = o1; out[ob + 2] = o2;
        pnew[m * 3 + 0] = o0; pnew[m * 3 + 1] = o1; pnew[m * 3 + 2] = o2;
        unsigned t[32];
#pragma unroll
        for (int i = 0; i < 32; ++i) t[i] = 0;
        t[0] = f2bf(o0); t[1] = f2bf(o1); t[2] = f2bf(o2);
        t[3] = f2bf(a0 - c0); t[4] = f2bf(a1 - c1); t[5] = f2bf(a2 - c2);
        t[6] = f2bf(o0 - 2.f * a0 + c0);
        t[7] = f2bf(o1 - 2.f * a1 + c1);
        t[8] = f2bf(o2 - 2.f * a2 + c2);
        t[9] = f2bf(1.f);
        uint4* dst = (uint4*)&xpad[(size_t)m * 32];
#pragma unroll
        for (int wq = 0; wq < 4; ++wq) {
            uint4 u;
            u.x = t[wq * 8 + 0] | (t[wq * 8 + 1] << 16);
            u.y = t[wq * 8 + 2] | (t[wq * 8 + 3] << 16);
            u.z = t[wq * 8 + 4] | (t[wq * 8 + 5] << 16);
            u.w = t[wq * 8 + 6] | (t[wq * 8 + 7] << 16);
            dst[wq] = u;
        }
    }
}

// ---------------------------------------------------------------------------
// Fused GRU, K=288: cols 0..255 = msg (Wh*), 256..287 = xpad (x-proj + bias).
// BYTE-EXACT R3 structure (115.5 us @ 20.4% occupancy, VGPR 116): rolled kt
// loop (NO unroll — R2's unroll cost 140 VGPR / 11% occ / 196 us), single
// LDS buffer, two barriers per K-step, constant-folded XOR swizzle.
// grid = (832, 4). DO NOT TOUCH. (R4/R5 slowdown to 143 us diagnosed as a
// ~20% clock reduction: all rate counters scale by 0.80 at identical
// occupancy/bytes/conflicts.)
// ---------------------------------------------------------------------------
__global__ __launch_bounds__(256) void gru_fused(
    const u16* __restrict__ Am, const u16* __restrict__ xpad,
    const u16* __restrict__ hprev, u16* __restrict__ hout,
    const u16* __restrict__ wfull, const u16* __restrict__ wxn)
{
    __shared__ u16 Al[128 * 32];   // 8 KB
    __shared__ u16 Bl[192 * 32];   // 12 KB
    __shared__ u16 Xl[64 * 32];    // 4 KB
    const int m0 = blockIdx.x * 128;
    const int n0 = blockIdx.y * 64;
    const int tid = threadIdx.x;
    const int wid = tid >> 6, lane = tid & 63;
    const int ln = lane & 15, q = lane >> 4;
    const int qs8 = (q ^ ((ln >> 1) & 3)) * 8;
    const int wm = (wid >> 1) * 64, wn = (wid & 1) * 32;
    const int srow = tid >> 2;
    const int spart = (tid & 3) ^ ((srow >> 1) & 3);

    // wxn tile (64 rows of this block's n0 slice), needed only at kt==8
    gl16(&wxn[(size_t)(n0 + srow) * 32 + spart * 8], &Xl[(wid * 64) * 8]);

    v4f accr[4][2] = {}, accz[4][2] = {}, acch[4][2] = {}, accn[4][2] = {};

    for (int kt = 0; kt < 9; ++kt) {
#pragma unroll
        for (int p = 0; p < 2; ++p) {
            const u16* ga = (kt < 8)
                ? &Am[(size_t)(m0 + p * 64 + srow) * 256 + kt * 32 + spart * 8]
                : &xpad[(size_t)(m0 + p * 64 + srow) * 32 + spart * 8];
            gl16(ga, &Al[(p * 256 + wid * 64) * 8]);
        }
#pragma unroll
        for (int p = 0; p < 3; ++p)
            gl16(&wfull[(size_t)(p * 256 + n0 + srow) * 288 + kt * 32 + spart * 8],
                 &Bl[(p * 256 + wid * 64) * 8]);
        __syncthreads();

        v8s af[4];
#pragma unroll
        for (int i = 0; i < 4; ++i)
            af[i] = *(const v8s*)&Al[(wm + i * 16 + ln) * 32 + qs8];
        v8s bfr[3][2];
#pragma unroll
        for (int g = 0; g < 3; ++g)
#pragma unroll
            for (int j = 0; j < 2; ++j)
                bfr[g][j] = *(const v8s*)&Bl[(g * 64 + wn + j * 16 + ln) * 32 + qs8];
#pragma unroll
        for (int i = 0; i < 4; ++i)
#pragma unroll
            for (int j = 0; j < 2; ++j) {
                accr[i][j] = __builtin_amdgcn_mfma_f32_16x16x32_bf16(af[i], bfr[0][j], accr[i][j], 0, 0, 0);
                accz[i][j] = __builtin_amdgcn_mfma_f32_16x16x32_bf16(af[i], bfr[1][j], accz[i][j], 0, 0, 0);
                acch[i][j] = __builtin_amdgcn_mfma_f32_16x16x32_bf16(af[i], bfr[2][j], acch[i][j], 0, 0, 0);
            }
        if (kt == 8) {
            v8s bfn[2];
#pragma unroll
            for (int j = 0; j < 2; ++j)
                bfn[j] = *(const v8s*)&Xl[(wn + j * 16 + ln) * 32 + qs8];
#pragma unroll
            for (int i = 0; i < 4; ++i)
#pragma unroll
                for (int j = 0; j < 2; ++j)
                    accn[i][j] = __builtin_amdgcn_mfma_f32_16x16x32_bf16(af[i], bfn[j], accn[i][j], 0, 0, 0);
        }
        __syncthreads();
    }

#pragma unroll
    for (int i = 0; i < 4; ++i)
#pragma unroll
        for (int j = 0; j < 2; ++j) {
            int gc = n0 + wn + j * 16 + ln;
#pragma unroll
            for (int r = 0; r < 4; ++r) {
                int gr = m0 + wm + i * 16 + q * 4 + r;
                float rg = sigm(accr[i][j][r]);
                float zg = sigm(accz[i][j][r]);
                float nn = tanh_fast(accn[i][j][r] + rg * acch[i][j][r]);
                float hp = bf2f(hprev[(size_t)gr * 256 + gc]);
                hout[(size_t)gr * 256 + gc] = f2bf((1.f - zg) * nn + zg * hp);
            }
        }
}

// ---------------------------------------------------------------------------
// Step-0 xpad from the three input frames.
// ---------------------------------------------------------------------------
__global__ __launch_bounds__(256) void init_xpad(
    const float* __restrict__ x0, const float* __restrict__ xp,
    const float* __restrict__ xp2, u16* __restrict__ xpad)
{
    int m = blockIdx.x * 256 + threadIdx.x;
    float a0 = x0[m * 3 + 0], a1 = x0[m * 3 + 1], a2 = x0[m * 3 + 2];
    float b0 = xp[m * 3 + 0], b1 = xp[m * 3 + 1], b2 = xp[m * 3 + 2];
    float c0 = xp2[m * 3 + 0], c1 = xp2[m * 3 + 1], c2 = xp2[m * 3 + 2];
    unsigned t[32];
#pragma unroll
    for (int i = 0; i < 32; ++i) t[i] = 0;
    t[0] = f2bf(a0); t[1] = f2bf(a1); t[2] = f2bf(a2);
    t[3] = f2bf(b0 - c0); t[4] = f2bf(b1 - c1); t[5] = f2bf(b2 - c2);
    t[6] = f2bf(a0 - 2.f * b0 + c0);
    t[7] = f2bf(a1 - 2.f * b1 + c1);
    t[8] = f2bf(a2 - 2.f * b2 + c2);
    t[9] = f2bf(1.f);
    uint4* dst = (uint4*)&xpad[(size_t)m * 32];
#pragma unroll
    for (int wq = 0; wq < 4; ++wq) {
        uint4 u;
        u.x = t[wq * 8 + 0] | (t[wq * 8 + 1] << 16);
        u.y = t[wq * 8 + 2] | (t[wq * 8 + 3] << 16);
        u.z = t[wq * 8 + 4] | (t[wq * 8 + 5] << 16);
        u.w = t[wq * 8 + 6] | (t[wq * 8 + 7] << 16);
        dst[wq] = u;
    }
}

// ---------------------------------------------------------------------------
// hidden [N,C,V] fp32 -> h[(n,v),c] bf16.
// ---------------------------------------------------------------------------
__global__ __launch_bounds__(256) void transpose_h(
    const float* __restrict__ hidden, u16* __restrict__ hA)
{
    __shared__ float hl[256 * VN];
    const int n = blockIdx.x, tid = threadIdx.x;
    const uint4* src = (const uint4*)(hidden + (size_t)n * 256 * VN);
    for (int idx = tid; idx < 256 * VN / 4; idx += 256)
        ((uint4*)hl)[idx] = src[idx];
    __syncthreads();
    size_t base = (size_t)n * VN * 256;
    for (int idx = tid; idx < VN * 256; idx += 256) {
        int v = idx >> 8, c = idx & 255;
        hA[base + idx] = f2bf(hl[c * VN + v]);
    }
}

// ---------------------------------------------------------------------------
// Weight packing (once per call).
// wfull[768,288]: row g*256+c -> cols 0..255 = Wh_g[c,:],
//   256..264 = x-weights (g<2), 265 = bias (g<2), rest 0.
// wxn[256,32]:   row c -> 0..8 = Win[c,:], 9 = b_in[c], rest 0.
// ---------------------------------------------------------------------------
__global__ __launch_bounds__(256) void pack_weights(
    const float* __restrict__ Whr, const float* __restrict__ Whi,
    const float* __restrict__ Whh, const float* __restrict__ convw_f,
    const float* __restrict__ W1f, const float* __restrict__ W2f,
    const float* __restrict__ Af, const float* __restrict__ emul,
    const float* __restrict__ eadd, const float* __restrict__ Wir,
    const float* __restrict__ Wii, const float* __restrict__ Win,
    const float* __restrict__ bir, const float* __restrict__ bii,
    const float* __restrict__ b_in, const float* __restrict__ convb_f,
    const float* __restrict__ b1f, const float* __restrict__ b2f,
    const float* __restrict__ W3f, const float* __restrict__ b3f,
    u16* __restrict__ wfull, u16* __restrict__ wxn, u16* __restrict__ convw,
    u16* __restrict__ w1, u16* __restrict__ w2, float* __restrict__ aadj,
    float* __restrict__ convb, float* __restrict__ b1, float* __restrict__ b2,
    float* __restrict__ w3, float* __restrict__ b3)
{
    int gid = blockIdx.x * 256 + threadIdx.x;
    int stride = gridDim.x * 256;
    for (int i = gid; i < 768 * 288; i += stride) {
        int row = i / 288, col = i - row * 288;
        int g = row >> 8, c = row & 255;
        float v = 0.f;
        if (col < 256)
            v = (g == 0 ? Whr : (g == 1 ? Whi : Whh))[c * 256 + col];
        else if (col < 265) {
            int tcol = col - 256;
            v = (g == 0 ? Wir[c * 9 + tcol] : (g == 1 ? Wii[c * 9 + tcol] : 0.f));
        } else if (col == 265)
            v = (g == 0 ? bir[c] : (g == 1 ? bii[c] : 0.f));
        wfull[i] = f2bf(v);
    }
    for (int i = gid; i < 256 * 32; i += stride) {
        int c = i >> 5, col = i & 31;
        float v = 0.f;
        if (col < 9) v = Win[c * 9 + col];
        else if (col == 9) v = b_in[c];
        wxn[i] = f2bf(v);
    }
    for (int i = gid; i < 65536; i += stride) {
        w1[i] = f2bf(W1f[i]);
        w2[i] = f2bf(W2f[i]);
    }
    for (int i = gid; i < 196608; i += stride) convw[i] = f2bf(convw_f[i]);
    for (int i = gid; i < KNUM * VN * VN; i += stride)
        aadj[i] = Af[i] * emul[i] + eadd[i];
    for (int i = gid; i < 256; i += stride) { b1[i] = b1f[i]; b2[i] = b2f[i]; }
    for (int i = gid; i < 768; i += stride) { convb[i] = convb_f[i]; w3[i] = W3f[i]; }
    if (gid < 3) b3[gid] = b3f[gid];
}

// ---------------------------------------------------------------------------
extern "C" void kernel_launch(void* const* d_in, const int* in_sizes, int n_in,
                              void* d_out, int out_size, void* d_ws, size_t ws_size,
                              hipStream_t stream)
{
    const float* inputs   = (const float*)d_in[0];
    const float* inputs_p = (const float*)d_in[1];
    const float* inputs_p2= (const float*)d_in[2];
    const float* hidden   = (const float*)d_in[3];
    const float* Af       = (const float*)d_in[4];
    const float* emul     = (const float*)d_in[5];
    const float* eadd     = (const float*)d_in[6];
    const float* conv_w   = (const float*)d_in[7];
    const float* conv_b   = (const float*)d_in[8];
    const float* Wir      = (const float*)d_in[9];
    const float* bir      = (const float*)d_in[10];
    const float* Wii      = (const float*)d_in[11];
    const float* bii      = (const float*)d_in[12];
    const float* Win      = (const float*)d_in[13];
    const float* b_in     = (const float*)d_in[14];
    const float* Whr      = (const float*)d_in[15];
    const float* Whi      = (const float*)d_in[16];
    const float* Whh      = (const float*)d_in[17];
    const float* W1f      = (const float*)d_in[18];
    const float* b1f      = (const float*)d_in[19];
    const float* W2f      = (const float*)d_in[20];
    const float* b2f      = (const float*)d_in[21];
    const float* W3f      = (const float*)d_in[22];
    const float* b3f      = (const float*)d_in[23];
    float* out = (float*)d_out;

    const size_t M = M_ROWS;
    char* ws = (char*)d_ws;
    size_t off = 0;
    auto alloc = [&](size_t bytes) -> void* {
        void* p = ws + off;
        off = (off + bytes + 255) & ~(size_t)255;
        return p;
    };
    // R3/R5-exact allocation order (gru's measured environment). ybuf is now
    // unused but kept so every later buffer keeps its address.
    u16* hA    = (u16*)alloc(M * 256 * 2);
    u16* hB    = (u16*)alloc(M * 256 * 2);
    u16* msg   = (u16*)alloc(M * 256 * 2);
    u16* ybuf  = (u16*)alloc(M * 768 * 2);
    u16* xpad  = (u16*)alloc(M * 32 * 2);
    float* pa  = (float*)alloc(M * 3 * 4);
    float* pb  = (float*)alloc(M * 3 * 4);
    float* pc  = (float*)alloc(M * 3 * 4);
    u16* wfull = (u16*)alloc(768 * 288 * 2);
    u16* wxn   = (u16*)alloc(256 * 32 * 2);
    u16* convw = (u16*)alloc(196608 * 2);
    u16* w1    = (u16*)alloc(65536 * 2);
    u16* w2    = (u16*)alloc(65536 * 2);
    float* aadj  = (float*)alloc(KNUM * VN * VN * 4);
    float* convb = (float*)alloc(768 * 4);
    float* b1    = (float*)alloc(256 * 4);
    float* b2    = (float*)alloc(256 * 4);
    float* w3    = (float*)alloc(768 * 4);
    float* b3    = (float*)alloc(16);
    (void)ybuf;
    if (off > ws_size) return;

    pack_weights<<<512, 256, 0, stream>>>(
        Whr, Whi, Whh, conv_w, W1f, W2f, Af, emul, eadd, Wir, Wii, Win,
        bir, bii, b_in, conv_b, b1f, b2f, W3f, b3f,
        wfull, wxn, convw, w1, w2, aadj, convb, b1, b2, w3, b3);
    transpose_h<<<NBATCH, 256, 0, stream>>>(hidden, hA);
    init_xpad<<<M_ROWS / 256, 256, 0, stream>>>(inputs, inputs_p, inputs_p2, xpad);
    hipMemcpyAsync(pa, inputs,    M * 3 * 4, hipMemcpyDeviceToDevice, stream);
    hipMemcpyAsync(pb, inputs_p,  M * 3 * 4, hipMemcpyDeviceToDevice, stream);
    hipMemcpyAsync(pc, inputs_p2, M * 3 * 4, hipMemcpyDeviceToDevice, stream);

    u16* hcur = hA;  u16* hnext = hB;
    float* P1 = pa;  float* P2 = pb;  float* P3 = pc;
    const int MB = M_ROWS / 128;  // 832

    for (int s = 0; s < TS; ++s) {
        const u16* m_ptr;
        if (s < 10) {
            // conv gemm + graph mix fused; y-panel stays in LDS
            conv_mix<<<NBATCH, 256, 0, stream>>>(hcur, convw, convb, aadj, msg);
            m_ptr = msg;
        } else {
            m_ptr = hcur;
        }
        gru_fused<<<dim3(MB, 4), 256, 0, stream>>>(m_ptr, xpad, hcur, hnext,
                                                   wfull, wxn);
        // W1+W2+W3+finisher fused: hd/hd2 never touch HBM
        mlp_head<<<M_ROWS / 64, 256, 0, stream>>>(hnext, w1, b1, w2, b2, w3, b3,
                                                  P1, P2, P3, xpad, out, s);
        float* t = P3; P3 = P2; P2 = P1; P1 = t;
        u16* ht = hcur; hcur = hnext; hnext = ht;
    }
}

// Round 7
// 5905.695 us; speedup vs baseline: 1.4112x; 1.0014x over previous
//
#include <hip/hip_runtime.h>

// Problem constants (fixed by the reference)
#define M_ROWS 106496   // 4096*26  (n,v) rows
#define NBATCH 4096
#define VN 26
#define KNUM 3
#define TS 25

typedef unsigned short u16;
typedef __attribute__((ext_vector_type(8))) short v8s;
typedef __attribute__((ext_vector_type(4))) float v4f;

__device__ __forceinline__ u16 f2bf(float f) {
    unsigned u = __float_as_uint(f);
    u += 0x7FFF + ((u >> 16) & 1);   // RNE
    return (u16)(u >> 16);
}
__device__ __forceinline__ float bf2f(u16 h) {
    return __uint_as_float(((unsigned)h) << 16);
}
__device__ __forceinline__ float sigm(float x) {
    return 1.f / (1.f + __expf(-x));
}
__device__ __forceinline__ float tanh_fast(float x) {
    return 2.f / (1.f + __expf(-2.f * x)) - 1.f;
}

// Async global->LDS, 16B per lane. LDS dest must be the wave-uniform base;
// HW adds lane*16. Staging layout stays LINEAR in lane order; the LDS
// swizzle is realized by pre-permuting the per-lane GLOBAL source chunk
// (rule: both-sides-or-neither with global_load_lds).
typedef const __attribute__((address_space(1))) unsigned int* gas_t;
typedef __attribute__((address_space(3))) unsigned int* las_t;
__device__ __forceinline__ void gl16(const void* g, void* l) {
    __builtin_amdgcn_global_load_lds((gas_t)g, (las_t)l, 16, 0, 0);
}

// ---------------------------------------------------------------------------
// Fused conv-gemm + graph mix, one block per batch n (R6 structure with two
// measured fixes):
//  (a) Hl re-tiled to [kt][32 rows][32 cols] + chunk-XOR swizzle — R6's flat
//      [32][256] had 512B row stride -> 16-way MFMA read conflicts (6.29M).
//  (b) aadj read from GLOBAL with wave-uniform address (s_load, L2-resident)
//      — R6's LDS copy put 2028 ds_read_b32/thread on the LDS pipe (~56 us).
// Output remains BITWISE-identical to the original gemm+graph_mix pair.
// LDS: Hl 16K + Yl 39K + Bst 24K = 79 KB -> 2 blocks/CU.
// ---------------------------------------------------------------------------
__global__ __launch_bounds__(256) void conv_mix(
    const u16* __restrict__ h, const u16* __restrict__ convw,
    const float* __restrict__ convb, const float* __restrict__ aadj,
    u16* __restrict__ msg)
{
    __shared__ u16 Hl[8 * 32 * 32];  // 16 KB: [kt][row][chunk-swizzled 32]
    __shared__ u16 Yl[26 * 768];     // 39 KB, chunk ^ (row&7) swizzled
    __shared__ u16 Bst[384 * 32];    // 24 KB weight tile
    const int n = blockIdx.x, tid = threadIdx.x;
    const int wid = tid >> 6, lane = tid & 63;
    const int ln = lane & 15, q = lane >> 4;
    const int qs8 = (q ^ ((ln >> 1) & 3)) * 8;
    const int wn = wid * 96;                 // 96 of 384 cols per wave
    const int srow = tid >> 2;
    const int spart = (tid & 3) ^ ((srow >> 1) & 3);

    // stage H tiled+swizzled via plain ds-writes; zero-pad rows 26..31
    for (int idx = tid; idx < 26 * 32; idx += 256) {
        int row = idx >> 5, g = idx & 31;            // g: global 8-col chunk
        uint4 v = *(const uint4*)&h[((size_t)n * 26 + row) * 256 + g * 8];
        int kt = g >> 2;                             // 32-col K-tile
        int gs = (g & 3) ^ ((row >> 1) & 3);         // swizzled chunk in tile
        *(uint4*)&Hl[kt * 1024 + row * 32 + gs * 8] = v;
    }
    {
        uint4 z = {0, 0, 0, 0};
        for (int idx = tid; idx < 6 * 32; idx += 256) {
            int row = 26 + (idx >> 5), g = idx & 31;
            *(uint4*)&Hl[(g >> 2) * 1024 + row * 32 + (g & 3) * 8] = z;
        }
    }

    const u16* gW0 = &convw[(size_t)srow * 256 + spart * 8];
    for (int p = 0; p < 2; ++p) {
        v4f acc[2][6] = {};
        const u16* gW = gW0 + (size_t)p * 384 * 256;
        for (int kt = 0; kt < 8; ++kt) {
#pragma unroll
            for (int t = 0; t < 6; ++t)
                gl16(gW + (size_t)t * 64 * 256 + kt * 32,
                     &Bst[t * 2048 + wid * 512]);
            __syncthreads();
            v8s af[2], bf[6];
#pragma unroll
            for (int i = 0; i < 2; ++i)
                af[i] = *(const v8s*)&Hl[kt * 1024 + (i * 16 + ln) * 32 + qs8];
#pragma unroll
            for (int j = 0; j < 6; ++j)
                bf[j] = *(const v8s*)&Bst[(wn + j * 16 + ln) * 32 + qs8];
#pragma unroll
            for (int i = 0; i < 2; ++i)
#pragma unroll
                for (int j = 0; j < 6; ++j)
                    acc[i][j] = __builtin_amdgcn_mfma_f32_16x16x32_bf16(
                        af[i], bf[j], acc[i][j], 0, 0, 0);
            __syncthreads();
        }
        // epilogue: y rows < 26 -> swizzled Yl (bf16, same rounding point
        // as the old ybuf store)
#pragma unroll
        for (int i = 0; i < 2; ++i)
#pragma unroll
            for (int j = 0; j < 6; ++j) {
                int o = p * 384 + wn + j * 16 + ln;
                float cb = convb[o];
#pragma unroll
                for (int r = 0; r < 4; ++r) {
                    int row = i * 16 + q * 4 + r;
                    if (row < 26) {
                        float v = acc[i][j][r] + cb;
                        int ch = (o >> 3) ^ (row & 7);
                        Yl[row * 768 + ch * 8 + (o & 7)] = f2bf(v);
                    }
                }
            }
    }
    __syncthreads();

    // graph mix: identical loop order / arithmetic to the original graph_mix;
    // aadj read from global (uniform addr -> scalar loads, L2-resident).
    const int c = tid;
    float accm[VN];
#pragma unroll
    for (int w = 0; w < VN; ++w) accm[w] = 0.f;
    for (int k = 0; k < KNUM; ++k)
        for (int v = 0; v < VN; ++v) {
            int o = k * 256 + c;
            float yv = bf2f(Yl[v * 768 + ((o >> 3) ^ (v & 7)) * 8 + (o & 7)]);
            const float* ap = &aadj[(k * VN + v) * VN];
#pragma unroll
            for (int w = 0; w < VN; ++w) accm[w] += yv * ap[w];
        }
    size_t base = (size_t)n * VN * 256;
#pragma unroll
    for (int w = 0; w < VN; ++w) msg[base + w * 256 + c] = f2bf(accm[w]);
}

// ---------------------------------------------------------------------------
// Fused MLP head: one kernel for W1 -> W2 -> W3 -> finisher (R5-exact,
// measured good). BM=64 rows/block, grid 1664. hd/hd2 never touch HBM.
// ---------------------------------------------------------------------------
__global__ __launch_bounds__(256) void mlp_head(
    const u16* __restrict__ A, const u16* __restrict__ w1,
    const float* __restrict__ b1, const u16* __restrict__ w2,
    const float* __restrict__ b2, const float* __restrict__ w3,
    const float* __restrict__ b3, const float* __restrict__ p1,
    const float* __restrict__ p2, float* __restrict__ pnew,
    u16* __restrict__ xpad, float* __restrict__ out, int s)
{
    __shared__ u16 Ast[2][64 * 32];     // 2 x 4 KB
    __shared__ u16 Bst[2][256 * 32];    // 2 x 16 KB
    __shared__ u16 hdl[64 * 256];       // 32 KB, chunk-XOR swizzled
    __shared__ float resl[2][64][3];    // 1.5 KB
    const int m0 = blockIdx.x * 64;
    const int tid = threadIdx.x;
    const int wid = tid >> 6, lane = tid & 63;
    const int ln = lane & 15, q = lane >> 4;
    const int qs8 = (q ^ ((ln >> 1) & 3)) * 8;
    const int wm = (wid >> 1) * 32;     // 0 / 32
    const int wn = (wid & 1) * 128;     // 0 / 128
    const int wnh = wid & 1;
    const int srow = tid >> 2;
    const int spart = (tid & 3) ^ ((srow >> 1) & 3);

    const u16* gA0 = &A[(size_t)(m0 + srow) * 256 + spart * 8];
    const u16* gW1 = &w1[(size_t)srow * 256 + spart * 8];
    const u16* gW2 = &w2[(size_t)srow * 256 + spart * 8];

#define STGA(b, kk) gl16(gA0 + (kk) * 32, &Ast[b][wid * 512])
#define STGB(b, kk, W) do {                                                 \
        gl16(W + (kk) * 32,             &Bst[b][wid * 512]);                \
        gl16(W + 64 * 256 + (kk) * 32,  &Bst[b][2048 + wid * 512]);         \
        gl16(W + 128 * 256 + (kk) * 32, &Bst[b][4096 + wid * 512]);         \
        gl16(W + 192 * 256 + (kk) * 32, &Bst[b][6144 + wid * 512]);         \
    } while (0)

    // ---- phase 1: acc = A @ W1^T ----
    v4f acc[2][8] = {};
    STGA(0, 0); STGB(0, 0, gW1);
    __syncthreads();
    for (int kt = 0; kt < 8; ++kt) {
        const int cb = kt & 1, nb = cb ^ 1;
        if (kt < 7) { STGA(nb, kt + 1); STGB(nb, kt + 1, gW1); }
        else        { STGB(nb, 0, gW2); }
        v8s af[2], bf[8];
#pragma unroll
        for (int i = 0; i < 2; ++i)
            af[i] = *(const v8s*)&Ast[cb][(wm + i * 16 + ln) * 32 + qs8];
#pragma unroll
        for (int j = 0; j < 8; ++j)
            bf[j] = *(const v8s*)&Bst[cb][(wn + j * 16 + ln) * 32 + qs8];
#pragma unroll
        for (int i = 0; i < 2; ++i)
#pragma unroll
            for (int j = 0; j < 8; ++j)
                acc[i][j] = __builtin_amdgcn_mfma_f32_16x16x32_bf16(
                    af[i], bf[j], acc[i][j], 0, 0, 0);
        __syncthreads();
    }

    // ---- epilogue 1: hd -> swizzled LDS ----
#pragma unroll
    for (int i = 0; i < 2; ++i)
#pragma unroll
        for (int j = 0; j < 8; ++j) {
            int col = wn + j * 16 + ln;
            float bb = b1[col];
#pragma unroll
            for (int r = 0; r < 4; ++r) {
                int row = wm + i * 16 + q * 4 + r;
                float v = acc[i][j][r] + bb;
                v = v > 0.f ? v : 0.1f * v;
                int ch = (col >> 3) ^ (row & 15);
                hdl[row * 256 + ch * 8 + (col & 7)] = f2bf(v);
            }
        }
    __syncthreads();

    // ---- phase 2: acc2 = hd @ W2^T ----
    v4f acc2[2][8] = {};
    for (int kt = 0; kt < 8; ++kt) {
        const int cb = kt & 1, nb = cb ^ 1;
        if (kt < 7) STGB(nb, kt + 1, gW2);
        v8s af[2], bf[8];
#pragma unroll
        for (int i = 0; i < 2; ++i) {
            int row = wm + i * 16 + ln;
            int ch = (kt * 4 + q) ^ (row & 15);
            af[i] = *(const v8s*)&hdl[row * 256 + ch * 8];
        }
#pragma unroll
        for (int j = 0; j < 8; ++j)
            bf[j] = *(const v8s*)&Bst[cb][(wn + j * 16 + ln) * 32 + qs8];
#pragma unroll
        for (int i = 0; i < 2; ++i)
#pragma unroll
            for (int j = 0; j < 8; ++j)
                acc2[i][j] = __builtin_amdgcn_mfma_f32_16x16x32_bf16(
                    af[i], bf[j], acc2[i][j], 0, 0, 0);
        __syncthreads();
    }
#undef STGA
#undef STGB

    // ---- epilogue 2: leaky + W3 partial dot + butterfly over ln ----
    float part[3][2][4] = {};
#pragma unroll
    for (int j = 0; j < 8; ++j) {
        int col = wn + j * 16 + ln;
        float bb = b2[col];
        float w30 = w3[col], w31 = w3[256 + col], w32 = w3[512 + col];
#pragma unroll
        for (int i = 0; i < 2; ++i)
#pragma unroll
            for (int r = 0; r < 4; ++r) {
                float v = acc2[i][j][r] + bb;
                v = v > 0.f ? v : 0.1f * v;
                part[0][i][r] += v * w30;
                part[1][i][r] += v * w31;
                part[2][i][r] += v * w32;
            }
    }
#pragma unroll
    for (int off = 1; off < 16; off <<= 1)
#pragma unroll
        for (int t = 0; t < 3; ++t)
#pragma unroll
            for (int i = 0; i < 2; ++i)
#pragma unroll
                for (int r = 0; r < 4; ++r)
                    part[t][i][r] += __shfl_xor(part[t][i][r], off, 16);
    if (ln == 0) {
#pragma unroll
        for (int i = 0; i < 2; ++i)
#pragma unroll
            for (int r = 0; r < 4; ++r) {
                int row = wm + i * 16 + q * 4 + r;
#pragma unroll
                for (int t = 0; t < 3; ++t)
                    resl[wnh][row][t] = part[t][i][r];
            }
    }
    __syncthreads();

    // ---- in-block finisher (64 threads, one row each) ----
    if (tid < 64) {
        int m = m0 + tid;
        float s0 = resl[0][tid][0] + resl[1][tid][0];
        float s1 = resl[0][tid][1] + resl[1][tid][1];
        float s2 = resl[0][tid][2] + resl[1][tid][2];
        float a0 = p1[m * 3 + 0], a1 = p1[m * 3 + 1], a2 = p1[m * 3 + 2];
        float c0 = p2[m * 3 + 0], c1 = p2[m * 3 + 1], c2 = p2[m * 3 + 2];
        float o0 = a0 + s0 + b3[0];
        float o1 = a1 + s1 + b3[1];
        float o2 = a2 + s2 + b3[2];
        size_t ob = ((size_t)m * TS + s) * 3;
        out[ob + 0] = o0; out[ob + 1] = o1; out[ob + 2] = o2;
        pnew[m * 3 + 0] = o0; pnew[m * 3 + 1] = o1; pnew[m * 3 + 2] = o2;
        unsigned t[32];
#pragma unroll
        for (int i = 0; i < 32; ++i) t[i] = 0;
        t[0] = f2bf(o0); t[1] = f2bf(o1); t[2] = f2bf(o2);
        t[3] = f2bf(a0 - c0); t[4] = f2bf(a1 - c1); t[5] = f2bf(a2 - c2);
        t[6] = f2bf(o0 - 2.f * a0 + c0);
        t[7] = f2bf(o1 - 2.f * a1 + c1);
        t[8] = f2bf(o2 - 2.f * a2 + c2);
        t[9] = f2bf(1.f);
        uint4* dst = (uint4*)&xpad[(size_t)m * 32];
#pragma unroll
        for (int wq = 0; wq < 4; ++wq) {
            uint4 u;
            u.x = t[wq * 8 + 0] | (t[wq * 8 + 1] << 16);
            u.y = t[wq * 8 + 2] | (t[wq * 8 + 3] << 16);
            u.z = t[wq * 8 + 4] | (t[wq * 8 + 5] << 16);
            u.w = t[wq * 8 + 6] | (t[wq * 8 + 7] << 16);
            dst[wq] = u;
        }
    }
}

// ---------------------------------------------------------------------------
// Fused GRU, K=288: cols 0..255 = msg (Wh*), 256..287 = xpad (x-proj + bias).
// BYTE-EXACT R3 structure (115.5 us @ 20.4% occupancy, VGPR 116): rolled kt
// loop (NO unroll — R2's unroll cost 140 VGPR / 11% occ / 196 us), single
// LDS buffer, two barriers per K-step, constant-folded XOR swizzle.
// grid = (832, 4). DO NOT TOUCH. (R4/R5 slowdown to 143 us diagnosed as a
// ~20% clock reduction: all rate counters scale by 0.80 at identical
// occupancy/bytes/conflicts.)
// ---------------------------------------------------------------------------
__global__ __launch_bounds__(256) void gru_fused(
    const u16* __restrict__ Am, const u16* __restrict__ xpad,
    const u16* __restrict__ hprev, u16* __restrict__ hout,
    const u16* __restrict__ wfull, const u16* __restrict__ wxn)
{
    __shared__ u16 Al[128 * 32];   // 8 KB
    __shared__ u16 Bl[192 * 32];   // 12 KB
    __shared__ u16 Xl[64 * 32];    // 4 KB
    const int m0 = blockIdx.x * 128;
    const int n0 = blockIdx.y * 64;
    const int tid = threadIdx.x;
    const int wid = tid >> 6, lane = tid & 63;
    const int ln = lane & 15, q = lane >> 4;
    const int qs8 = (q ^ ((ln >> 1) & 3)) * 8;
    const int wm = (wid >> 1) * 64, wn = (wid & 1) * 32;
    const int srow = tid >> 2;
    const int spart = (tid & 3) ^ ((srow >> 1) & 3);

    // wxn tile (64 rows of this block's n0 slice), needed only at kt==8
    gl16(&wxn[(size_t)(n0 + srow) * 32 + spart * 8], &Xl[(wid * 64) * 8]);

    v4f accr[4][2] = {}, accz[4][2] = {}, acch[4][2] = {}, accn[4][2] = {};

    for (int kt = 0; kt < 9; ++kt) {
#pragma unroll
        for (int p = 0; p < 2; ++p) {
            const u16* ga = (kt < 8)
                ? &Am[(size_t)(m0 + p * 64 + srow) * 256 + kt * 32 + spart * 8]
                : &xpad[(size_t)(m0 + p * 64 + srow) * 32 + spart * 8];
            gl16(ga, &Al[(p * 256 + wid * 64) * 8]);
        }
#pragma unroll
        for (int p = 0; p < 3; ++p)
            gl16(&wfull[(size_t)(p * 256 + n0 + srow) * 288 + kt * 32 + spart * 8],
                 &Bl[(p * 256 + wid * 64) * 8]);
        __syncthreads();

        v8s af[4];
#pragma unroll
        for (int i = 0; i < 4; ++i)
            af[i] = *(const v8s*)&Al[(wm + i * 16 + ln) * 32 + qs8];
        v8s bfr[3][2];
#pragma unroll
        for (int g = 0; g < 3; ++g)
#pragma unroll
            for (int j = 0; j < 2; ++j)
                bfr[g][j] = *(const v8s*)&Bl[(g * 64 + wn + j * 16 + ln) * 32 + qs8];
#pragma unroll
        for (int i = 0; i < 4; ++i)
#pragma unroll
            for (int j = 0; j < 2; ++j) {
                accr[i][j] = __builtin_amdgcn_mfma_f32_16x16x32_bf16(af[i], bfr[0][j], accr[i][j], 0, 0, 0);
                accz[i][j] = __builtin_amdgcn_mfma_f32_16x16x32_bf16(af[i], bfr[1][j], accz[i][j], 0, 0, 0);
                acch[i][j] = __builtin_amdgcn_mfma_f32_16x16x32_bf16(af[i], bfr[2][j], acch[i][j], 0, 0, 0);
            }
        if (kt == 8) {
            v8s bfn[2];
#pragma unroll
            for (int j = 0; j < 2; ++j)
                bfn[j] = *(const v8s*)&Xl[(wn + j * 16 + ln) * 32 + qs8];
#pragma unroll
            for (int i = 0; i < 4; ++i)
#pragma unroll
                for (int j = 0; j < 2; ++j)
                    accn[i][j] = __builtin_amdgcn_mfma_f32_16x16x32_bf16(af[i], bfn[j], accn[i][j], 0, 0, 0);
        }
        __syncthreads();
    }

#pragma unroll
    for (int i = 0; i < 4; ++i)
#pragma unroll
        for (int j = 0; j < 2; ++j) {
            int gc = n0 + wn + j * 16 + ln;
#pragma unroll
            for (int r = 0; r < 4; ++r) {
                int gr = m0 + wm + i * 16 + q * 4 + r;
                float rg = sigm(accr[i][j][r]);
                float zg = sigm(accz[i][j][r]);
                float nn = tanh_fast(accn[i][j][r] + rg * acch[i][j][r]);
                float hp = bf2f(hprev[(size_t)gr * 256 + gc]);
                hout[(size_t)gr * 256 + gc] = f2bf((1.f - zg) * nn + zg * hp);
            }
        }
}

// ---------------------------------------------------------------------------
// Step-0 xpad from the three input frames.
// ---------------------------------------------------------------------------
__global__ __launch_bounds__(256) void init_xpad(
    const float* __restrict__ x0, const float* __restrict__ xp,
    const float* __restrict__ xp2, u16* __restrict__ xpad)
{
    int m = blockIdx.x * 256 + threadIdx.x;
    float a0 = x0[m * 3 + 0], a1 = x0[m * 3 + 1], a2 = x0[m * 3 + 2];
    float b0 = xp[m * 3 + 0], b1 = xp[m * 3 + 1], b2 = xp[m * 3 + 2];
    float c0 = xp2[m * 3 + 0], c1 = xp2[m * 3 + 1], c2 = xp2[m * 3 + 2];
    unsigned t[32];
#pragma unroll
    for (int i = 0; i < 32; ++i) t[i] = 0;
    t[0] = f2bf(a0); t[1] = f2bf(a1); t[2] = f2bf(a2);
    t[3] = f2bf(b0 - c0); t[4] = f2bf(b1 - c1); t[5] = f2bf(b2 - c2);
    t[6] = f2bf(a0 - 2.f * b0 + c0);
    t[7] = f2bf(a1 - 2.f * b1 + c1);
    t[8] = f2bf(a2 - 2.f * b2 + c2);
    t[9] = f2bf(1.f);
    uint4* dst = (uint4*)&xpad[(size_t)m * 32];
#pragma unroll
    for (int wq = 0; wq < 4; ++wq) {
        uint4 u;
        u.x = t[wq * 8 + 0] | (t[wq * 8 + 1] << 16);
        u.y = t[wq * 8 + 2] | (t[wq * 8 + 3] << 16);
        u.z = t[wq * 8 + 4] | (t[wq * 8 + 5] << 16);
        u.w = t[wq * 8 + 6] | (t[wq * 8 + 7] << 16);
        dst[wq] = u;
    }
}

// ---------------------------------------------------------------------------
// hidden [N,C,V] fp32 -> h[(n,v),c] bf16.
// ---------------------------------------------------------------------------
__global__ __launch_bounds__(256) void transpose_h(
    const float* __restrict__ hidden, u16* __restrict__ hA)
{
    __shared__ float hl[256 * VN];
    const int n = blockIdx.x, tid = threadIdx.x;
    const uint4* src = (const uint4*)(hidden + (size_t)n * 256 * VN);
    for (int idx = tid; idx < 256 * VN / 4; idx += 256)
        ((uint4*)hl)[idx] = src[idx];
    __syncthreads();
    size_t base = (size_t)n * VN * 256;
    for (int idx = tid; idx < VN * 256; idx += 256) {
        int v = idx >> 8, c = idx & 255;
        hA[base + idx] = f2bf(hl[c * VN + v]);
    }
}

// ---------------------------------------------------------------------------
// Weight packing (once per call).
// wfull[768,288]: row g*256+c -> cols 0..255 = Wh_g[c,:],
//   256..264 = x-weights (g<2), 265 = bias (g<2), rest 0.
// wxn[256,32]:   row c -> 0..8 = Win[c,:], 9 = b_in[c], rest 0.
// ---------------------------------------------------------------------------
__global__ __launch_bounds__(256) void pack_weights(
    const float* __restrict__ Whr, const float* __restrict__ Whi,
    const float* __restrict__ Whh, const float* __restrict__ convw_f,
    const float* __restrict__ W1f, const float* __restrict__ W2f,
    const float* __restrict__ Af, const float* __restrict__ emul,
    const float* __restrict__ eadd, const float* __restrict__ Wir,
    const float* __restrict__ Wii, const float* __restrict__ Win,
    const float* __restrict__ bir, const float* __restrict__ bii,
    const float* __restrict__ b_in, const float* __restrict__ convb_f,
    const float* __restrict__ b1f, const float* __restrict__ b2f,
    const float* __restrict__ W3f, const float* __restrict__ b3f,
    u16* __restrict__ wfull, u16* __restrict__ wxn, u16* __restrict__ convw,
    u16* __restrict__ w1, u16* __restrict__ w2, float* __restrict__ aadj,
    float* __restrict__ convb, float* __restrict__ b1, float* __restrict__ b2,
    float* __restrict__ w3, float* __restrict__ b3)
{
    int gid = blockIdx.x * 256 + threadIdx.x;
    int stride = gridDim.x * 256;
    for (int i = gid; i < 768 * 288; i += stride) {
        int row = i / 288, col = i - row * 288;
        int g = row >> 8, c = row & 255;
        float v = 0.f;
        if (col < 256)
            v = (g == 0 ? Whr : (g == 1 ? Whi : Whh))[c * 256 + col];
        else if (col < 265) {
            int tcol = col - 256;
            v = (g == 0 ? Wir[c * 9 + tcol] : (g == 1 ? Wii[c * 9 + tcol] : 0.f));
        } else if (col == 265)
            v = (g == 0 ? bir[c] : (g == 1 ? bii[c] : 0.f));
        wfull[i] = f2bf(v);
    }
    for (int i = gid; i < 256 * 32; i += stride) {
        int c = i >> 5, col = i & 31;
        float v = 0.f;
        if (col < 9) v = Win[c * 9 + col];
        else if (col == 9) v = b_in[c];
        wxn[i] = f2bf(v);
    }
    for (int i = gid; i < 65536; i += stride) {
        w1[i] = f2bf(W1f[i]);
        w2[i] = f2bf(W2f[i]);
    }
    for (int i = gid; i < 196608; i += stride) convw[i] = f2bf(convw_f[i]);
    for (int i = gid; i < KNUM * VN * VN; i += stride)
        aadj[i] = Af[i] * emul[i] + eadd[i];
    for (int i = gid; i < 256; i += stride) { b1[i] = b1f[i]; b2[i] = b2f[i]; }
    for (int i = gid; i < 768; i += stride) { convb[i] = convb_f[i]; w3[i] = W3f[i]; }
    if (gid < 3) b3[gid] = b3f[gid];
}

// ---------------------------------------------------------------------------
extern "C" void kernel_launch(void* const* d_in, const int* in_sizes, int n_in,
                              void* d_out, int out_size, void* d_ws, size_t ws_size,
                              hipStream_t stream)
{
    const float* inputs   = (const float*)d_in[0];
    const float* inputs_p = (const float*)d_in[1];
    const float* inputs_p2= (const float*)d_in[2];
    const float* hidden   = (const float*)d_in[3];
    const float* Af       = (const float*)d_in[4];
    const float* emul     = (const float*)d_in[5];
    const float* eadd     = (const float*)d_in[6];
    const float* conv_w   = (const float*)d_in[7];
    const float* conv_b   = (const float*)d_in[8];
    const float* Wir      = (const float*)d_in[9];
    const float* bir      = (const float*)d_in[10];
    const float* Wii      = (const float*)d_in[11];
    const float* bii      = (const float*)d_in[12];
    const float* Win      = (const float*)d_in[13];
    const float* b_in     = (const float*)d_in[14];
    const float* Whr      = (const float*)d_in[15];
    const float* Whi      = (const float*)d_in[16];
    const float* Whh      = (const float*)d_in[17];
    const float* W1f      = (const float*)d_in[18];
    const float* b1f      = (const float*)d_in[19];
    const float* W2f      = (const float*)d_in[20];
    const float* b2f      = (const float*)d_in[21];
    const float* W3f      = (const float*)d_in[22];
    const float* b3f      = (const float*)d_in[23];
    float* out = (float*)d_out;

    const size_t M = M_ROWS;
    char* ws = (char*)d_ws;
    size_t off = 0;
    auto alloc = [&](size_t bytes) -> void* {
        void* p = ws + off;
        off = (off + bytes + 255) & ~(size_t)255;
        return p;
    };
    // R3/R5-exact allocation order (gru's measured environment). ybuf is now
    // unused but kept so every later buffer keeps its address.
    u16* hA    = (u16*)alloc(M * 256 * 2);
    u16* hB    = (u16*)alloc(M * 256 * 2);
    u16* msg   = (u16*)alloc(M * 256 * 2);
    u16* ybuf  = (u16*)alloc(M * 768 * 2);
    u16* xpad  = (u16*)alloc(M * 32 * 2);
    float* pa  = (float*)alloc(M * 3 * 4);
    float* pb  = (float*)alloc(M * 3 * 4);
    float* pc  = (float*)alloc(M * 3 * 4);
    u16* wfull = (u16*)alloc(768 * 288 * 2);
    u16* wxn   = (u16*)alloc(256 * 32 * 2);
    u16* convw = (u16*)alloc(196608 * 2);
    u16* w1    = (u16*)alloc(65536 * 2);
    u16* w2    = (u16*)alloc(65536 * 2);
    float* aadj  = (float*)alloc(KNUM * VN * VN * 4);
    float* convb = (float*)alloc(768 * 4);
    float* b1    = (float*)alloc(256 * 4);
    float* b2    = (float*)alloc(256 * 4);
    float* w3    = (float*)alloc(768 * 4);
    float* b3    = (float*)alloc(16);
    (void)ybuf;
    if (off > ws_size) return;

    pack_weights<<<512, 256, 0, stream>>>(
        Whr, Whi, Whh, conv_w, W1f, W2f, Af, emul, eadd, Wir, Wii, Win,
        bir, bii, b_in, conv_b, b1f, b2f, W3f, b3f,
        wfull, wxn, convw, w1, w2, aadj, convb, b1, b2, w3, b3);
    transpose_h<<<NBATCH, 256, 0, stream>>>(hidden, hA);
    init_xpad<<<M_ROWS / 256, 256, 0, stream>>>(inputs, inputs_p, inputs_p2, xpad);
    hipMemcpyAsync(pa, inputs,    M * 3 * 4, hipMemcpyDeviceToDevice, stream);
    hipMemcpyAsync(pb, inputs_p,  M * 3 * 4, hipMemcpyDeviceToDevice, stream);
    hipMemcpyAsync(pc, inputs_p2, M * 3 * 4, hipMemcpyDeviceToDevice, stream);

    u16* hcur = hA;  u16* hnext = hB;
    float* P1 = pa;  float* P2 = pb;  float* P3 = pc;
    const int MB = M_ROWS / 128;  // 832

    for (int s = 0; s < TS; ++s) {
        const u16* m_ptr;
        if (s < 10) {
            // conv gemm + graph mix fused; y-panel stays in LDS
            conv_mix<<<NBATCH, 256, 0, stream>>>(hcur, convw, convb, aadj, msg);
            m_ptr = msg;
        } else {
            m_ptr = hcur;
        }
        gru_fused<<<dim3(MB, 4), 256, 0, stream>>>(m_ptr, xpad, hcur, hnext,
                                                   wfull, wxn);
        // W1+W2+W3+finisher fused: hd/hd2 never touch HBM
        mlp_head<<<M_ROWS / 64, 256, 0, stream>>>(hnext, w1, b1, w2, b2, w3, b3,
                                                  P1, P2, P3, xpad, out, s);
        float* t = P3; P3 = P2; P2 = P1; P1 = t;
        u16* ht = hcur; hcur = hnext; hnext = ht;
    }
}